// Round 3
// baseline (6172.406 us; speedup 1.0000x reference)
//
#include <hip/hip_runtime.h>
#include <hip/hip_bf16.h>
#include <stdint.h>

#define NLAYERS 8
#define LSEQ 576
#define EMB 768
#define NHEAD 12
#define HDIM 64
#define FFDIM 3072
#define BLROWS 4608   // B*L

typedef __attribute__((ext_vector_type(8))) short short8;
typedef __attribute__((ext_vector_type(4))) float floatx4;

__device__ __forceinline__ float b2f(short s) {
    union { float f; uint32_t u; } x; x.u = ((uint32_t)(uint16_t)s) << 16; return x.f;
}
__device__ __forceinline__ short f2b(float f) {
    union { float f; uint32_t u; } x; x.f = f;
    uint32_t r = x.u + 0x7fffu + ((x.u >> 16) & 1u);
    return (short)(r >> 16);
}

#define GLDS16(gp, lp) __builtin_amdgcn_global_load_lds( \
    (const __attribute__((address_space(1))) void*)(gp), \
    (__attribute__((address_space(3))) void*)(lp), 16, 0, 0)

// ---------------- GEMM: C[M,N] = A[M,K](bf16) * Bt[N,K]^T (bf16) + epilogue ----------------
// grid = (N/128, M/128), block = 256 (4 waves, 2x2 of 64x64 per wave)
template<bool ADD_POS, bool RES_F32, bool LEAKY, bool OUT_F32>
__global__ __launch_bounds__(256)
void gemm_bt(const short* __restrict__ A, const short* __restrict__ Bt,
             const float* __restrict__ bias, const float* __restrict__ pos,
             const float* __restrict__ resf, void* __restrict__ Cout,
             int N, int K)
{
    __shared__ short As[128 * 32];
    __shared__ short Bs[128 * 32];
    const int t    = threadIdx.x;
    const int lane = t & 63;
    const int w    = t >> 6;
    const int m0   = blockIdx.y * 128;
    const int n0   = blockIdx.x * 128;
    const int wm   = (w >> 1) * 64;
    const int wn   = (w & 1) * 64;

    floatx4 acc[4][4];
#pragma unroll
    for (int i = 0; i < 4; ++i)
#pragma unroll
        for (int j = 0; j < 4; ++j)
            acc[i][j] = (floatx4){0.f, 0.f, 0.f, 0.f};

    const int sr = t >> 2;          // staging row within 64-row half
    const int sc = (t & 3) * 8;     // staging k-offset (8 bf16 = 16B)
    const short* Ag = A  + (size_t)(m0 + sr) * K + sc;
    const short* Bg = Bt + (size_t)(n0 + sr) * K + sc;
    short* As0 = &As[(size_t)t * 8];
    short* As1 = &As[(size_t)(t + 256) * 8];
    short* Bs0 = &Bs[(size_t)t * 8];
    short* Bs1 = &Bs[(size_t)(t + 256) * 8];

    for (int k0 = 0; k0 < K; k0 += 32) {
        GLDS16(Ag + k0,                  As0);
        GLDS16(Ag + (size_t)64 * K + k0, As1);
        GLDS16(Bg + k0,                  Bs0);
        GLDS16(Bg + (size_t)64 * K + k0, Bs1);
        __syncthreads();   // drains vmcnt -> staged data visible
        short8 af[4], bf[4];
#pragma unroll
        for (int i = 0; i < 4; ++i) {
            af[i] = *(const short8*)&As[(wm + i * 16 + (lane & 15)) * 32 + (lane >> 4) * 8];
            bf[i] = *(const short8*)&Bs[(wn + i * 16 + (lane & 15)) * 32 + (lane >> 4) * 8];
        }
#pragma unroll
        for (int i = 0; i < 4; ++i)
#pragma unroll
            for (int j = 0; j < 4; ++j)
                acc[i][j] = __builtin_amdgcn_mfma_f32_16x16x32_bf16(af[i], bf[j], acc[i][j], 0, 0, 0);
        __syncthreads();   // protect LDS before next-iter staging
    }

    const int colb = n0 + wn + (lane & 15);
    const int rowb = m0 + wm + ((lane >> 4) * 4);
#pragma unroll
    for (int i = 0; i < 4; ++i) {
#pragma unroll
        for (int j = 0; j < 4; ++j) {
            const int col = colb + j * 16;
            const float bv = bias[col];
#pragma unroll
            for (int r = 0; r < 4; ++r) {
                const int row = rowb + i * 16 + r;
                float v = acc[i][j][r] + bv;
                if constexpr (ADD_POS) v += pos[(size_t)(row % LSEQ) * N + col];
                if constexpr (RES_F32) v += resf[(size_t)row * N + col];
                if constexpr (LEAKY)   v = v >= 0.f ? v : 0.01f * v;
                if constexpr (OUT_F32) ((float*)Cout)[(size_t)row * N + col] = v;
                else                   ((short*)Cout)[(size_t)row * N + col] = f2b(v);
            }
        }
    }
}

// ---------------- LayerNorm over E=768, input f32, outputs bf16 (+optional f32 copy) ----------------
__global__ __launch_bounds__(256)
void ln_kernel(const float* __restrict__ h, const float* __restrict__ g,
               const float* __restrict__ bbias, short* __restrict__ outb,
               float* __restrict__ outf)
{
    const int row = blockIdx.x;
    const float* x = h + (size_t)row * EMB;
    const int t = threadIdx.x;
    float v0 = x[t], v1 = x[t + 256], v2 = x[t + 512];
    float s  = v0 + v1 + v2;
    float ss = v0 * v0 + v1 * v1 + v2 * v2;
#pragma unroll
    for (int m = 1; m < 64; m <<= 1) {
        s  += __shfl_xor(s, m, 64);
        ss += __shfl_xor(ss, m, 64);
    }
    __shared__ float red[8];
    if ((t & 63) == 0) { red[t >> 6] = s; red[4 + (t >> 6)] = ss; }
    __syncthreads();
    float S  = red[0] + red[1] + red[2] + red[3];
    float SS = red[4] + red[5] + red[6] + red[7];
    float mean = S * (1.f / 768.f);
    float var  = SS * (1.f / 768.f) - mean * mean;
    float rstd = rsqrtf(var + 1e-5f);
    const size_t base = (size_t)row * EMB;
#pragma unroll
    for (int q = 0; q < 3; ++q) {
        int e = t + q * 256;
        float v = (q == 0 ? v0 : (q == 1 ? v1 : v2));
        float y = (v - mean) * rstd * g[e] + bbias[e];
        outb[base + e] = f2b(y);
        if (outf) outf[base + e] = y;
    }
}

// ---------------- Fused attention, online softmax. grid=(9, NH, B), block=256 ----------------
// thread = (query q = t>>2 within 64-block, dim-group dg = t&3 covering 16 of 64 dims)
__global__ __launch_bounds__(256)
void attn_kernel(const short* __restrict__ qkv, short* __restrict__ oout, int causal)
{
    const int qb = blockIdx.x, hh = blockIdx.y, b = blockIdx.z;
    const int t = threadIdx.x;
    const int ql = t >> 2;
    const int dg = t & 3;
    const int l = qb * 64 + ql;   // global query pos

    __shared__ float Ks[64][65];
    __shared__ float Vs[64][65];

    float qreg[16];
    const short* qp = qkv + (size_t)(b * LSEQ + l) * 2304 + hh * 64 + dg * 16;
    {
        short8 a = *(const short8*)qp;
        short8 c = *(const short8*)(qp + 8);
#pragma unroll
        for (int j = 0; j < 8; ++j) { qreg[j] = b2f(a[j]) * 0.125f; qreg[8 + j] = b2f(c[j]) * 0.125f; }
    }

    float mx = -1e30f, lsum = 0.f;
    float o_acc[16];
#pragma unroll
    for (int j = 0; j < 16; ++j) o_acc[j] = 0.f;

    const int ktmax = causal ? qb : 8;
    for (int kt = 0; kt <= ktmax; ++kt) {
        __syncthreads();   // previous-iter reads done before overwrite
        {
            const int rr = t >> 2;
            const int cc = (t & 3) * 16;
            const short* kp = qkv + (size_t)(b * LSEQ + kt * 64 + rr) * 2304 + 768 + hh * 64 + cc;
            const short* vp = kp + 768;
            short8 ka = *(const short8*)kp,        kb = *(const short8*)(kp + 8);
            short8 va = *(const short8*)vp,        vb = *(const short8*)(vp + 8);
#pragma unroll
            for (int j = 0; j < 8; ++j) {
                Ks[rr][cc + j]     = b2f(ka[j]);
                Ks[rr][cc + 8 + j] = b2f(kb[j]);
                Vs[rr][cc + j]     = b2f(va[j]);
                Vs[rr][cc + 8 + j] = b2f(vb[j]);
            }
        }
        __syncthreads();
        int kkmax = 64;
        if (causal && kt == qb) kkmax = ql + 1;
        for (int kk = 0; kk < kkmax; ++kk) {
            float part = 0.f;
#pragma unroll
            for (int j = 0; j < 16; ++j) part = fmaf(qreg[j], Ks[kk][dg * 16 + j], part);
            part += __shfl_xor(part, 1, 64);
            part += __shfl_xor(part, 2, 64);
            const float sv = part;
            if (sv <= mx) {
                float p = __expf(sv - mx);
                lsum += p;
#pragma unroll
                for (int j = 0; j < 16; ++j) o_acc[j] = fmaf(p, Vs[kk][dg * 16 + j], o_acc[j]);
            } else {
                float c = __expf(mx - sv);
                mx = sv;
                lsum = fmaf(lsum, c, 1.f);
#pragma unroll
                for (int j = 0; j < 16; ++j) o_acc[j] = fmaf(o_acc[j], c, Vs[kk][dg * 16 + j]);
            }
        }
    }
    const float inv = 1.f / lsum;
    // faithful torch reshape: (B, NH, L, hd) flat -> viewed as (B, L, E)
    short* op = oout + (size_t)b * LSEQ * EMB + (size_t)hh * LSEQ * HDIM + (size_t)l * HDIM + dg * 16;
#pragma unroll
    for (int j = 0; j < 16; ++j) op[j] = f2b(o_acc[j] * inv);
}

// ---------------- transposes ----------------
// f32 in -> bf16 out, per-batch: out[b][C][R] = in[b][R][C]^T
__global__ void transpose_f2b(const float* __restrict__ in, short* __restrict__ out,
                              int R, int C, long long ibs, long long obs)
{
    __shared__ float tile[32][33];
    const int b = blockIdx.z;
    const float* inb = in + (long long)b * ibs;
    short* outb = out + (long long)b * obs;
    const int r0 = blockIdx.y * 32, c0 = blockIdx.x * 32;
    const int tx = threadIdx.x, ty = threadIdx.y;
#pragma unroll
    for (int i = 0; i < 32; i += 8) tile[ty + i][tx] = inb[(size_t)(r0 + ty + i) * C + c0 + tx];
    __syncthreads();
#pragma unroll
    for (int i = 0; i < 32; i += 8) outb[(size_t)(c0 + ty + i) * R + r0 + tx] = f2b(tile[tx][ty + i]);
}

// f32 in -> f32 out transpose (final output scramble)
__global__ void transpose_f2f(const float* __restrict__ in, float* __restrict__ out,
                              int R, int C, long long ibs, long long obs)
{
    __shared__ float tile[32][33];
    const int b = blockIdx.z;
    const float* inb = in + (long long)b * ibs;
    float* outb = out + (long long)b * obs;
    const int r0 = blockIdx.y * 32, c0 = blockIdx.x * 32;
    const int tx = threadIdx.x, ty = threadIdx.y;
#pragma unroll
    for (int i = 0; i < 32; i += 8) tile[ty + i][tx] = inb[(size_t)(r0 + ty + i) * C + c0 + tx];
    __syncthreads();
#pragma unroll
    for (int i = 0; i < 32; i += 8) outb[(size_t)(c0 + ty + i) * R + r0 + tx] = tile[tx][ty + i];
}

// ---------------- misc small kernels ----------------
__global__ void concat_qkv_bias(const float* __restrict__ bq, const float* __restrict__ bk,
                                const float* __restrict__ bv, float* __restrict__ out)
{
    int i = blockIdx.x * 256 + threadIdx.x;          // NLAYERS*2304
    int layer = i / 2304, j = i % 2304;
    float v;
    if (j < 768)       v = bq[layer * 768 + j];
    else if (j < 1536) v = bk[layer * 768 + j - 768];
    else               v = bv[layer * 768 + j - 1536];
    out[i] = v;
}

__global__ void im2col_kernel(const float* __restrict__ x, short* __restrict__ xcol)
{
    const size_t idx = (size_t)blockIdx.x * 256 + threadIdx.x;   // 4608*768
    const int k = (int)(idx % 768);
    const size_t m = idx / 768;
    const int c  = k >> 8;
    const int ky = (k >> 4) & 15;
    const int kx = k & 15;
    const int b  = (int)(m / 576);
    const int l  = (int)(m % 576);
    const int ph = l / 24, pw = l % 24;
    xcol[idx] = f2b(x[((size_t)(b * 3 + c) * 384 + ph * 16 + ky) * 384 + pw * 16 + kx]);
}

__global__ void cast_f32_b16(const float* __restrict__ in, short* __restrict__ out, int n)
{
    int i = blockIdx.x * 256 + threadIdx.x;
    if (i < n) out[i] = f2b(in[i]);
}

// ---------------- host launcher ----------------
extern "C" void kernel_launch(void* const* d_in, const int* in_sizes, int n_in,
                              void* d_out, int out_size, void* d_ws, size_t ws_size,
                              hipStream_t stream)
{
    const float* x      = (const float*)d_in[0];
    const float* conv_w = (const float*)d_in[1];
    const float* conv_b = (const float*)d_in[2];
    const float* pos    = (const float*)d_in[3];
    const float* ln0_s  = (const float*)d_in[4];
    const float* ln0_b  = (const float*)d_in[5];
    const float* Wq     = (const float*)d_in[6];
    const float* bq     = (const float*)d_in[7];
    const float* Wk     = (const float*)d_in[8];
    const float* bk     = (const float*)d_in[9];
    const float* Wv     = (const float*)d_in[10];
    const float* bv     = (const float*)d_in[11];
    const float* Wo     = (const float*)d_in[12];
    const float* bo     = (const float*)d_in[13];
    const float* ln1_s  = (const float*)d_in[14];
    const float* ln1_b  = (const float*)d_in[15];
    const float* W1     = (const float*)d_in[16];
    const float* b1     = (const float*)d_in[17];
    const float* W2     = (const float*)d_in[18];
    const float* b2     = (const float*)d_in[19];
    const float* proj_w = (const float*)d_in[20];
    const float* proj_b = (const float*)d_in[21];

    char* ws = (char*)d_ws;
    short* qkvT  = (short*)(ws);                    // [8][2304][768] bf16
    short* woT   = (short*)(ws + 28311552);         // [8][768][768]
    short* w1T   = (short*)(ws + 37748736);         // [8][3072][768]
    short* w2T   = (short*)(ws + 75497472);         // [8][768][3072]
    short* projT = (short*)(ws + 113246208);        // [768][768]
    float* qkvb  = (float*)(ws + 114425856);        // [8][2304] f32
    short* tmpA  = (short*)(ws + 114499584);        // xcol / m1 bf16 [4608][3072] max; yf f32 at end
    float* h     = (float*)(ws + 142811136);        // residual stream f32 [4608][768]
    short* xn    = (short*)(ws + 156966912);        // LN0 out bf16; hb at end
    short* xrb   = (short*)(ws + 164044800);        // LN1 out bf16
    float* xrf   = (float*)(ws + 171122688);        // LN1 out f32
    short* qkv   = (short*)(ws + 185278464);        // [4608][2304] bf16
    short* o     = (short*)(ws + 206512128);        // attn out (scrambled) bf16
    short* convB = (short*)(ws + 213590016);        // conv_w cast bf16 [768][768]

    dim3 tb(32, 8);
    // weight pre-transposes (f32 -> bf16, N-major Bt layout)
    transpose_f2b<<<dim3(24, 24, 8), tb, 0, stream>>>(Wq, qkvT,           768, 768, 589824, 1769472);
    transpose_f2b<<<dim3(24, 24, 8), tb, 0, stream>>>(Wk, qkvT + 589824,  768, 768, 589824, 1769472);
    transpose_f2b<<<dim3(24, 24, 8), tb, 0, stream>>>(Wv, qkvT + 1179648, 768, 768, 589824, 1769472);
    transpose_f2b<<<dim3(24, 24, 8), tb, 0, stream>>>(Wo, woT,            768, 768, 589824, 589824);
    transpose_f2b<<<dim3(96, 24, 8), tb, 0, stream>>>(W1, w1T,            768, 3072, 2359296, 2359296);
    transpose_f2b<<<dim3(24, 96, 8), tb, 0, stream>>>(W2, w2T,            3072, 768, 2359296, 2359296);
    transpose_f2b<<<dim3(24, 24, 1), tb, 0, stream>>>(proj_w, projT,      768, 768, 0, 0);
    cast_f32_b16<<<2304, 256, 0, stream>>>(conv_w, convB, 589824);
    concat_qkv_bias<<<72, 256, 0, stream>>>(bq, bk, bv, qkvb);

    // patch embed: im2col + GEMM(convB as Bt) + conv_b + pos  -> h (f32)
    im2col_kernel<<<13824, 256, 0, stream>>>(x, tmpA);
    gemm_bt<true, false, false, true><<<dim3(6, 36), 256, 0, stream>>>(
        tmpA, convB, conv_b, pos, nullptr, h, 768, 768);

    for (int i = 0; i < NLAYERS; ++i) {
        ln_kernel<<<4608, 256, 0, stream>>>(h, ln0_s + i * 768, ln0_b + i * 768, xn, nullptr);
        gemm_bt<false, false, false, false><<<dim3(18, 36), 256, 0, stream>>>(
            xn, qkvT + (size_t)i * 1769472, qkvb + i * 2304, nullptr, nullptr, qkv, 2304, 768);
        attn_kernel<<<dim3(9, 12, 8), 256, 0, stream>>>(qkv, o, i == 0 ? 1 : 0);
        gemm_bt<false, true, false, true><<<dim3(6, 36), 256, 0, stream>>>(
            o, woT + (size_t)i * 589824, bo + i * 768, nullptr, h, h, 768, 768);
        ln_kernel<<<4608, 256, 0, stream>>>(h, ln1_s + i * 768, ln1_b + i * 768, xrb, xrf);
        gemm_bt<false, false, true, false><<<dim3(24, 36), 256, 0, stream>>>(
            xrb, w1T + (size_t)i * 2359296, b1 + i * 3072, nullptr, nullptr, tmpA, 3072, 768);
        gemm_bt<false, true, false, true><<<dim3(6, 36), 256, 0, stream>>>(
            tmpA, w2T + (size_t)i * 2359296, b2 + i * 768, nullptr, xrf, h, 768, 3072);
    }

    // final projection + output scramble (B, L, CPP) -> (B, CPP, L) flat
    short* hb = xn;              // reuse (free after loop)
    float* yf = (float*)tmpA;    // reuse (free after loop)
    cast_f32_b16<<<13824, 256, 0, stream>>>(h, hb, 4608 * 768);
    gemm_bt<false, false, false, true><<<dim3(6, 36), 256, 0, stream>>>(
        hb, projT, proj_b, nullptr, nullptr, yf, 768, 768);
    transpose_f2f<<<dim3(24, 18, 8), tb, 0, stream>>>(yf, (float*)d_out, 576, 768, 442368, 442368);
}

// Round 4
// 2022.038 us; speedup vs baseline: 3.0526x; 3.0526x over previous
//
#include <hip/hip_runtime.h>
#include <hip/hip_bf16.h>
#include <stdint.h>

#define NLAYERS 8
#define LSEQ 576
#define EMB 768
#define NHEAD 12
#define HDIM 64
#define FFDIM 3072
#define BLROWS 4608   // B*L

typedef __attribute__((ext_vector_type(8))) short short8;
typedef __attribute__((ext_vector_type(4))) float floatx4;

__device__ __forceinline__ float b2f(short s) {
    union { float f; uint32_t u; } x; x.u = ((uint32_t)(uint16_t)s) << 16; return x.f;
}
__device__ __forceinline__ short f2b(float f) {
    union { float f; uint32_t u; } x; x.f = f;
    uint32_t r = x.u + 0x7fffu + ((x.u >> 16) & 1u);
    return (short)(r >> 16);
}

#define GLDS16(gp, lp) __builtin_amdgcn_global_load_lds( \
    (const __attribute__((address_space(1))) void*)(gp), \
    (__attribute__((address_space(3))) void*)(lp), 16, 0, 0)

// ---------------- GEMM: C[M,N] = A[M,K](bf16) * Bt[N,K]^T (bf16) + epilogue ----------------
template<bool ADD_POS, bool RES_F32, bool LEAKY, bool OUT_F32>
__global__ __launch_bounds__(256)
void gemm_bt(const short* __restrict__ A, const short* __restrict__ Bt,
             const float* __restrict__ bias, const float* __restrict__ pos,
             const float* __restrict__ resf, void* __restrict__ Cout,
             int N, int K)
{
    __shared__ short As[128 * 32];
    __shared__ short Bs[128 * 32];
    const int t    = threadIdx.x;
    const int lane = t & 63;
    const int w    = t >> 6;
    const int m0   = blockIdx.y * 128;
    const int n0   = blockIdx.x * 128;
    const int wm   = (w >> 1) * 64;
    const int wn   = (w & 1) * 64;

    floatx4 acc[4][4];
#pragma unroll
    for (int i = 0; i < 4; ++i)
#pragma unroll
        for (int j = 0; j < 4; ++j)
            acc[i][j] = (floatx4){0.f, 0.f, 0.f, 0.f};

    const int sr = t >> 2;
    const int sc = (t & 3) * 8;
    const short* Ag = A  + (size_t)(m0 + sr) * K + sc;
    const short* Bg = Bt + (size_t)(n0 + sr) * K + sc;
    short* As0 = &As[(size_t)t * 8];
    short* As1 = &As[(size_t)(t + 256) * 8];
    short* Bs0 = &Bs[(size_t)t * 8];
    short* Bs1 = &Bs[(size_t)(t + 256) * 8];

    for (int k0 = 0; k0 < K; k0 += 32) {
        GLDS16(Ag + k0,                  As0);
        GLDS16(Ag + (size_t)64 * K + k0, As1);
        GLDS16(Bg + k0,                  Bs0);
        GLDS16(Bg + (size_t)64 * K + k0, Bs1);
        __syncthreads();
        short8 af[4], bf[4];
#pragma unroll
        for (int i = 0; i < 4; ++i) {
            af[i] = *(const short8*)&As[(wm + i * 16 + (lane & 15)) * 32 + (lane >> 4) * 8];
            bf[i] = *(const short8*)&Bs[(wn + i * 16 + (lane & 15)) * 32 + (lane >> 4) * 8];
        }
#pragma unroll
        for (int i = 0; i < 4; ++i)
#pragma unroll
            for (int j = 0; j < 4; ++j)
                acc[i][j] = __builtin_amdgcn_mfma_f32_16x16x32_bf16(af[i], bf[j], acc[i][j], 0, 0, 0);
        __syncthreads();
    }

    const int colb = n0 + wn + (lane & 15);
    const int rowb = m0 + wm + ((lane >> 4) * 4);
#pragma unroll
    for (int i = 0; i < 4; ++i) {
#pragma unroll
        for (int j = 0; j < 4; ++j) {
            const int col = colb + j * 16;
            const float bv = bias[col];
#pragma unroll
            for (int r = 0; r < 4; ++r) {
                const int row = rowb + i * 16 + r;
                float v = acc[i][j][r] + bv;
                if constexpr (ADD_POS) v += pos[(size_t)(row % LSEQ) * N + col];
                if constexpr (RES_F32) v += resf[(size_t)row * N + col];
                if constexpr (LEAKY)   v = v >= 0.f ? v : 0.01f * v;
                if constexpr (OUT_F32) ((float*)Cout)[(size_t)row * N + col] = v;
                else                   ((short*)Cout)[(size_t)row * N + col] = f2b(v);
            }
        }
    }
}

// ---------------- LayerNorm over E=768, input f32, outputs bf16 (+optional f32 copy) ----------------
__global__ __launch_bounds__(256)
void ln_kernel(const float* __restrict__ h, const float* __restrict__ g,
               const float* __restrict__ bbias, short* __restrict__ outb,
               float* __restrict__ outf)
{
    const int row = blockIdx.x;
    const float* x = h + (size_t)row * EMB;
    const int t = threadIdx.x;
    float v0 = x[t], v1 = x[t + 256], v2 = x[t + 512];
    float s  = v0 + v1 + v2;
    float ss = v0 * v0 + v1 * v1 + v2 * v2;
#pragma unroll
    for (int m = 1; m < 64; m <<= 1) {
        s  += __shfl_xor(s, m, 64);
        ss += __shfl_xor(ss, m, 64);
    }
    __shared__ float red[8];
    if ((t & 63) == 0) { red[t >> 6] = s; red[4 + (t >> 6)] = ss; }
    __syncthreads();
    float S  = red[0] + red[1] + red[2] + red[3];
    float SS = red[4] + red[5] + red[6] + red[7];
    float mean = S * (1.f / 768.f);
    float var  = SS * (1.f / 768.f) - mean * mean;
    float rstd = rsqrtf(var + 1e-5f);
    const size_t base = (size_t)row * EMB;
#pragma unroll
    for (int q = 0; q < 3; ++q) {
        int e = t + q * 256;
        float v = (q == 0 ? v0 : (q == 1 ? v1 : v2));
        float y = (v - mean) * rstd * g[e] + bbias[e];
        outb[base + e] = f2b(y);
        if (outf) outf[base + e] = y;
    }
}

// ---------------- per-layer K/V repack: kp[bh][l][d] (row-swizzled), vt[bh][d][l] (row-swizzled) ----
// grid (9, 96), block 256. Swizzle: element (n, e) stored at n*64 + (e ^ ((n&7)<<3)) within 64-tiles.
__global__ __launch_bounds__(256)
void repack_kv(const short* __restrict__ qkv, short* __restrict__ kp, short* __restrict__ vt)
{
    const int kt = blockIdx.x, bh = blockIdx.y;
    const int b = bh / 12, h = bh % 12;
    const int t = threadIdx.x;
    // K: row copy with chunk permutation (reads & writes coalesced)
#pragma unroll
    for (int i = 0; i < 2; ++i) {
        int flat = i * 256 + t;
        int key = flat >> 3, c = flat & 7;
        short8 vK = *(const short8*)(qkv + ((size_t)(b * LSEQ) + kt * 64 + key) * 2304 + 768 + h * 64 + c * 8);
        *(short8*)(kp + ((size_t)bh * LSEQ + kt * 64 + key) * 64 + 8 * (c ^ (key & 7))) = vK;
    }
    // V: 64x64 transpose via LDS, swizzled on the k index within the tile
    __shared__ short tile[64][65];
    const int tx = t & 63, ty = t >> 6;
#pragma unroll
    for (int r = 0; r < 16; ++r) {
        int k = ty * 16 + r;
        tile[k][tx] = qkv[((size_t)(b * LSEQ) + kt * 64 + k) * 2304 + 1536 + h * 64 + tx];
    }
    __syncthreads();
#pragma unroll
    for (int r = 0; r < 16; ++r) {
        int d = ty * 16 + r;
        vt[((size_t)bh * 64 + d) * LSEQ + kt * 64 + (tx ^ ((d & 7) << 3))] = tile[tx][d];
    }
}

// ---------------- MFMA flash attention. grid (9 qtiles, 96 bh), block 256 = 4 waves ----------------
// wave w: 16-query strip. Per K-tile: QK^T (8 mfma) -> online softmax -> P via LDS -> PV (8 mfma).
__global__ __launch_bounds__(256)
void attn_mfma(const short* __restrict__ qkv, const short* __restrict__ kp,
               const short* __restrict__ vt, short* __restrict__ oout, int causal)
{
    const int qt = blockIdx.x, bh = blockIdx.y;
    const int b = bh / 12, h = bh % 12;
    const int t = threadIdx.x, lane = t & 63, w = t >> 6;

    __shared__ short Ks[64 * 64];
    __shared__ short Vs[64 * 64];
    __shared__ short Plds[4][16][72];

    const int nrow = lane & 15;          // n within 16-tile (key / d)
    const int kch  = (lane >> 4) * 8;    // k-chunk base within 32
    const int swz  = (lane & 7) << 3;    // stored-swizzle XOR for LDS reads

    // Q A-fragments (row = query in strip, k = head dim)
    short8 aq[2];
    {
        const short* qrow = qkv + ((size_t)(b * LSEQ) + qt * 64 + w * 16 + nrow) * 2304 + h * 64 + kch;
        aq[0] = *(const short8*)qrow;
        aq[1] = *(const short8*)(qrow + 32);
    }

    float m[4], lsum[4];
    floatx4 oacc[4];
#pragma unroll
    for (int r = 0; r < 4; ++r) { m[r] = -3e38f; lsum[r] = 0.f; }
#pragma unroll
    for (int j = 0; j < 4; ++j) oacc[j] = (floatx4){0.f, 0.f, 0.f, 0.f};

    const int ktend = causal ? qt : 8;
    const short* ksrc = kp + ((size_t)bh * LSEQ) * 64;
    const short* vsrc = vt + ((size_t)bh * 64) * LSEQ;

    for (int kt = 0; kt <= ktend; ++kt) {
        __syncthreads();   // all waves done reading previous tile
        {
            const short* kt_src = ksrc + (size_t)(kt * 64) * 64;   // contiguous 8KB
            GLDS16(kt_src + (size_t)t * 8,          &Ks[(size_t)t * 8]);
            GLDS16(kt_src + (size_t)(t + 256) * 8,  &Ks[(size_t)(t + 256) * 8]);
            int f0 = t, f1 = t + 256;
            GLDS16(vsrc + (size_t)(f0 >> 3) * LSEQ + kt * 64 + (f0 & 7) * 8, &Vs[(size_t)f0 * 8]);
            GLDS16(vsrc + (size_t)(f1 >> 3) * LSEQ + kt * 64 + (f1 & 7) * 8, &Vs[(size_t)f1 * 8]);
        }
        __syncthreads();   // staged data visible

        // QK^T: S strip 16x64
        floatx4 sc[4];
#pragma unroll
        for (int j = 0; j < 4; ++j) sc[j] = (floatx4){0.f, 0.f, 0.f, 0.f};
#pragma unroll
        for (int s = 0; s < 2; ++s) {
#pragma unroll
            for (int j = 0; j < 4; ++j) {
                short8 bk = *(const short8*)&Ks[(16 * j + nrow) * 64 + ((kch + 32 * s) ^ swz)];
                sc[j] = __builtin_amdgcn_mfma_f32_16x16x32_bf16(aq[s], bk, sc[j], 0, 0, 0);
            }
        }
        // scale + causal mask
        float sv[4][4];
#pragma unroll
        for (int j = 0; j < 4; ++j)
#pragma unroll
            for (int r = 0; r < 4; ++r) {
                float v = sc[j][r] * 0.125f;
                if (causal && kt == qt) {
                    int key = kt * 64 + 16 * j + nrow;
                    int qr  = qt * 64 + w * 16 + (lane >> 4) * 4 + r;
                    if (key > qr) v = -1e12f;
                }
                sv[j][r] = v;
            }
        // online softmax per row r
#pragma unroll
        for (int r = 0; r < 4; ++r) {
            float tm = fmaxf(fmaxf(sv[0][r], sv[1][r]), fmaxf(sv[2][r], sv[3][r]));
            tm = fmaxf(tm, __shfl_xor(tm, 1, 64));
            tm = fmaxf(tm, __shfl_xor(tm, 2, 64));
            tm = fmaxf(tm, __shfl_xor(tm, 4, 64));
            tm = fmaxf(tm, __shfl_xor(tm, 8, 64));
            float nm = fmaxf(m[r], tm);
            float c  = __expf(m[r] - nm);
            m[r] = nm;
            float ps = 0.f;
#pragma unroll
            for (int j = 0; j < 4; ++j) {
                float p = __expf(sv[j][r] - nm);
                sv[j][r] = p;
                ps += p;
            }
            lsum[r] = lsum[r] * c + ps;
#pragma unroll
            for (int j = 0; j < 4; ++j) oacc[j][r] *= c;
        }
        // P -> LDS (own-wave buffer; intra-wave lgkmcnt orders write->read)
#pragma unroll
        for (int j = 0; j < 4; ++j)
#pragma unroll
            for (int r = 0; r < 4; ++r)
                Plds[w][(lane >> 4) * 4 + r][16 * j + nrow] = f2b(sv[j][r]);
        short8 ap[2];
#pragma unroll
        for (int s = 0; s < 2; ++s)
            ap[s] = *(const short8*)&Plds[w][nrow][kch + 32 * s];
        // PV: O strip 16x64 (+= P . Vt^T)
#pragma unroll
        for (int s = 0; s < 2; ++s) {
#pragma unroll
            for (int j = 0; j < 4; ++j) {
                short8 bv = *(const short8*)&Vs[(16 * j + nrow) * 64 + ((kch + 32 * s) ^ swz)];
                oacc[j] = __builtin_amdgcn_mfma_f32_16x16x32_bf16(ap[s], bv, oacc[j], 0, 0, 0);
            }
        }
    }

    // epilogue: finish l, write scrambled (B, NH, L, hd) layout
    float inv[4];
#pragma unroll
    for (int r = 0; r < 4; ++r) {
        float L = lsum[r];
        L += __shfl_xor(L, 1, 64);
        L += __shfl_xor(L, 2, 64);
        L += __shfl_xor(L, 4, 64);
        L += __shfl_xor(L, 8, 64);
        inv[r] = 1.f / L;
    }
#pragma unroll
    for (int j = 0; j < 4; ++j)
#pragma unroll
        for (int r = 0; r < 4; ++r) {
            size_t lq = (size_t)qt * 64 + w * 16 + (lane >> 4) * 4 + r;
            oout[((size_t)bh * LSEQ + lq) * 64 + 16 * j + nrow] = f2b(oacc[j][r] * inv[r]);
        }
}

// ---------------- transposes ----------------
__global__ void transpose_f2b(const float* __restrict__ in, short* __restrict__ out,
                              int R, int C, long long ibs, long long obs)
{
    __shared__ float tile[32][33];
    const int b = blockIdx.z;
    const float* inb = in + (long long)b * ibs;
    short* outb = out + (long long)b * obs;
    const int r0 = blockIdx.y * 32, c0 = blockIdx.x * 32;
    const int tx = threadIdx.x, ty = threadIdx.y;
#pragma unroll
    for (int i = 0; i < 32; i += 8) tile[ty + i][tx] = inb[(size_t)(r0 + ty + i) * C + c0 + tx];
    __syncthreads();
#pragma unroll
    for (int i = 0; i < 32; i += 8) outb[(size_t)(c0 + ty + i) * R + r0 + tx] = f2b(tile[tx][ty + i]);
}

__global__ void transpose_f2f(const float* __restrict__ in, float* __restrict__ out,
                              int R, int C, long long ibs, long long obs)
{
    __shared__ float tile[32][33];
    const int b = blockIdx.z;
    const float* inb = in + (long long)b * ibs;
    float* outb = out + (long long)b * obs;
    const int r0 = blockIdx.y * 32, c0 = blockIdx.x * 32;
    const int tx = threadIdx.x, ty = threadIdx.y;
#pragma unroll
    for (int i = 0; i < 32; i += 8) tile[ty + i][tx] = inb[(size_t)(r0 + ty + i) * C + c0 + tx];
    __syncthreads();
#pragma unroll
    for (int i = 0; i < 32; i += 8) outb[(size_t)(c0 + ty + i) * R + r0 + tx] = tile[tx][ty + i];
}

// ---------------- misc small kernels ----------------
__global__ void concat_qkv_bias(const float* __restrict__ bq, const float* __restrict__ bk,
                                const float* __restrict__ bv, float* __restrict__ out)
{
    int i = blockIdx.x * 256 + threadIdx.x;
    int layer = i / 2304, j = i % 2304;
    float v;
    if (j < 768)       v = bq[layer * 768 + j];
    else if (j < 1536) v = bk[layer * 768 + j - 768];
    else               v = bv[layer * 768 + j - 1536];
    out[i] = v;
}

__global__ void im2col_kernel(const float* __restrict__ x, short* __restrict__ xcol)
{
    const size_t idx = (size_t)blockIdx.x * 256 + threadIdx.x;
    const int k = (int)(idx % 768);
    const size_t m = idx / 768;
    const int c  = k >> 8;
    const int ky = (k >> 4) & 15;
    const int kx = k & 15;
    const int b  = (int)(m / 576);
    const int l  = (int)(m % 576);
    const int ph = l / 24, pw = l % 24;
    xcol[idx] = f2b(x[((size_t)(b * 3 + c) * 384 + ph * 16 + ky) * 384 + pw * 16 + kx]);
}

__global__ void cast_f32_b16(const float* __restrict__ in, short* __restrict__ out, int n)
{
    int i = blockIdx.x * 256 + threadIdx.x;
    if (i < n) out[i] = f2b(in[i]);
}

// ---------------- host launcher ----------------
extern "C" void kernel_launch(void* const* d_in, const int* in_sizes, int n_in,
                              void* d_out, int out_size, void* d_ws, size_t ws_size,
                              hipStream_t stream)
{
    const float* x      = (const float*)d_in[0];
    const float* conv_w = (const float*)d_in[1];
    const float* conv_b = (const float*)d_in[2];
    const float* pos    = (const float*)d_in[3];
    const float* ln0_s  = (const float*)d_in[4];
    const float* ln0_b  = (const float*)d_in[5];
    const float* Wq     = (const float*)d_in[6];
    const float* bq     = (const float*)d_in[7];
    const float* Wk     = (const float*)d_in[8];
    const float* bk     = (const float*)d_in[9];
    const float* Wv     = (const float*)d_in[10];
    const float* bv     = (const float*)d_in[11];
    const float* Wo     = (const float*)d_in[12];
    const float* bo     = (const float*)d_in[13];
    const float* ln1_s  = (const float*)d_in[14];
    const float* ln1_b  = (const float*)d_in[15];
    const float* W1     = (const float*)d_in[16];
    const float* b1     = (const float*)d_in[17];
    const float* W2     = (const float*)d_in[18];
    const float* b2     = (const float*)d_in[19];
    const float* proj_w = (const float*)d_in[20];
    const float* proj_b = (const float*)d_in[21];

    char* ws = (char*)d_ws;
    short* qkvT  = (short*)(ws);                    // [8][2304][768] bf16
    short* woT   = (short*)(ws + 28311552);         // [8][768][768]
    short* w1T   = (short*)(ws + 37748736);         // [8][3072][768]
    short* w2T   = (short*)(ws + 75497472);         // [8][768][3072]
    short* projT = (short*)(ws + 113246208);        // [768][768]
    float* qkvb  = (float*)(ws + 114425856);        // [8][2304] f32
    short* tmpA  = (short*)(ws + 114499584);        // xcol / m1 bf16 [4608][3072]; kp/vt overlay; yf f32
    float* h     = (float*)(ws + 142811136);        // residual stream f32 [4608][768]
    short* xn    = (short*)(ws + 156966912);        // LN0 out bf16; hb at end
    short* xrb   = (short*)(ws + 164044800);        // LN1 out bf16
    float* xrf   = (float*)(ws + 171122688);        // LN1 out f32
    short* qkv   = (short*)(ws + 185278464);        // [4608][2304] bf16
    short* o     = (short*)(ws + 206512128);        // attn out (scrambled) bf16
    short* convB = (short*)(ws + 213590016);        // conv_w cast bf16 [768][768]

    // kp/vt overlay inside tmpA region (free between qkv-GEMM and MLP GEMM1)
    short* kp = tmpA;                               // [96][576][64] bf16 (7077888 B)
    short* vt = tmpA + 3538944;                     // [96][64][576] bf16 (7077888 B)

    dim3 tb(32, 8);
    transpose_f2b<<<dim3(24, 24, 8), tb, 0, stream>>>(Wq, qkvT,           768, 768, 589824, 1769472);
    transpose_f2b<<<dim3(24, 24, 8), tb, 0, stream>>>(Wk, qkvT + 589824,  768, 768, 589824, 1769472);
    transpose_f2b<<<dim3(24, 24, 8), tb, 0, stream>>>(Wv, qkvT + 1179648, 768, 768, 589824, 1769472);
    transpose_f2b<<<dim3(24, 24, 8), tb, 0, stream>>>(Wo, woT,            768, 768, 589824, 589824);
    transpose_f2b<<<dim3(96, 24, 8), tb, 0, stream>>>(W1, w1T,            768, 3072, 2359296, 2359296);
    transpose_f2b<<<dim3(24, 96, 8), tb, 0, stream>>>(W2, w2T,            3072, 768, 2359296, 2359296);
    transpose_f2b<<<dim3(24, 24, 1), tb, 0, stream>>>(proj_w, projT,      768, 768, 0, 0);
    cast_f32_b16<<<2304, 256, 0, stream>>>(conv_w, convB, 589824);
    concat_qkv_bias<<<72, 256, 0, stream>>>(bq, bk, bv, qkvb);

    // patch embed: im2col + GEMM(convB as Bt) + conv_b + pos  -> h (f32)
    im2col_kernel<<<13824, 256, 0, stream>>>(x, tmpA);
    gemm_bt<true, false, false, true><<<dim3(6, 36), 256, 0, stream>>>(
        tmpA, convB, conv_b, pos, nullptr, h, 768, 768);

    for (int i = 0; i < NLAYERS; ++i) {
        ln_kernel<<<4608, 256, 0, stream>>>(h, ln0_s + i * 768, ln0_b + i * 768, xn, nullptr);
        gemm_bt<false, false, false, false><<<dim3(18, 36), 256, 0, stream>>>(
            xn, qkvT + (size_t)i * 1769472, qkvb + i * 2304, nullptr, nullptr, qkv, 2304, 768);
        repack_kv<<<dim3(9, 96), 256, 0, stream>>>(qkv, kp, vt);
        attn_mfma<<<dim3(9, 96), 256, 0, stream>>>(qkv, kp, vt, o, i == 0 ? 1 : 0);
        gemm_bt<false, true, false, true><<<dim3(6, 36), 256, 0, stream>>>(
            o, woT + (size_t)i * 589824, bo + i * 768, nullptr, h, h, 768, 768);
        ln_kernel<<<4608, 256, 0, stream>>>(h, ln1_s + i * 768, ln1_b + i * 768, xrb, xrf);
        gemm_bt<false, false, true, false><<<dim3(24, 36), 256, 0, stream>>>(
            xrb, w1T + (size_t)i * 2359296, b1 + i * 3072, nullptr, nullptr, tmpA, 3072, 768);
        gemm_bt<false, true, false, true><<<dim3(6, 36), 256, 0, stream>>>(
            tmpA, w2T + (size_t)i * 2359296, b2 + i * 768, nullptr, xrf, h, 768, 3072);
    }

    // final projection + output scramble (B, L, CPP) -> (B, CPP, L) flat
    short* hb = xn;
    float* yf = (float*)tmpA;
    cast_f32_b16<<<13824, 256, 0, stream>>>(h, hb, 4608 * 768);
    gemm_bt<false, false, false, true><<<dim3(6, 36), 256, 0, stream>>>(
        hb, projT, proj_b, nullptr, nullptr, yf, 768, 768);
    transpose_f2f<<<dim3(24, 18, 8), tb, 0, stream>>>(yf, (float*)d_out, 576, 768, 442368, 442368);
}

// Round 7
// 1796.164 us; speedup vs baseline: 3.4364x; 1.1258x over previous
//
#include <hip/hip_runtime.h>
#include <hip/hip_bf16.h>
#include <stdint.h>

#define NLAYERS 8
#define LSEQ 576
#define EMB 768
#define NHEAD 12
#define HDIM 64
#define FFDIM 3072
#define BLROWS 4608   // B*L

typedef __attribute__((ext_vector_type(8))) short short8;
typedef __attribute__((ext_vector_type(4))) float floatx4;

__device__ __forceinline__ float b2f(short s) {
    union { float f; uint32_t u; } x; x.u = ((uint32_t)(uint16_t)s) << 16; return x.f;
}
__device__ __forceinline__ short f2b(float f) {
    union { float f; uint32_t u; } x; x.f = f;
    uint32_t r = x.u + 0x7fffu + ((x.u >> 16) & 1u);
    return (short)(r >> 16);
}

#define GLDS16(gp, lp) __builtin_amdgcn_global_load_lds( \
    (const __attribute__((address_space(1))) void*)(gp), \
    (__attribute__((address_space(3))) void*)(lp), 16, 0, 0)

// bijective XCD-chunked remap (m204): each XCD gets a contiguous range of the
// linear block index (bx fastest) -> A-panel rows stay resident in one XCD's L2.
__device__ __forceinline__ void xcd_remap(int& bx, int& by) {
    const int gx = gridDim.x;
    const int n  = gx * gridDim.y;
    const int orig = by * gx + bx;
    const int q = n >> 3, r = n & 7;
    const int xcd = orig & 7;
    const int wgid = (xcd < r ? xcd * (q + 1) : r * (q + 1) + (xcd - r) * q) + (orig >> 3);
    bx = wgid % gx;
    by = wgid / gx;
}

// ---------------- GEMM: C[M,N] = A[M,K](bf16) * Bt[N,K]^T (bf16) + epilogue ----------------
// BM = MF*32 (MF=4 -> 128x128 tile; MF=2 -> 64x128 tile for grid inflation on narrow N).
// block = 256 (4 waves, 2x2 of (MF*16)x64 per wave)
template<int MF, bool ADD_POS, bool RES_F32, bool LEAKY, bool OUT_F32>
__global__ __launch_bounds__(256)
void gemm_bt(const short* __restrict__ A, const short* __restrict__ Bt,
             const float* __restrict__ bias, const float* __restrict__ pos,
             const float* __restrict__ resf, void* __restrict__ Cout,
             int N, int K)
{
    constexpr int BM = MF * 32;
    __shared__ short As[BM * 32];
    __shared__ short Bs[128 * 32];
    int bx = blockIdx.x, by = blockIdx.y;
    xcd_remap(bx, by);
    const int t    = threadIdx.x;
    const int lane = t & 63;
    const int w    = t >> 6;
    const int m0   = by * BM;
    const int n0   = bx * 128;
    const int wm   = (w >> 1) * (MF * 16);
    const int wn   = (w & 1) * 64;

    floatx4 acc[MF][4];
#pragma unroll
    for (int i = 0; i < MF; ++i)
#pragma unroll
        for (int j = 0; j < 4; ++j)
            acc[i][j] = (floatx4){0.f, 0.f, 0.f, 0.f};

    const int sr = t >> 2;          // staging row within 64-row half
    const int sc = (t & 3) * 8;     // staging k-offset (8 bf16 = 16B)
    const short* Ag = A  + (size_t)(m0 + sr) * K + sc;
    const short* Bg = Bt + (size_t)(n0 + sr) * K + sc;

    for (int k0 = 0; k0 < K; k0 += 32) {
        GLDS16(Ag + k0, &As[(size_t)t * 8]);
        if constexpr (MF == 4)
            GLDS16(Ag + (size_t)64 * K + k0, &As[(size_t)(t + 256) * 8]);
        GLDS16(Bg + k0,                  &Bs[(size_t)t * 8]);
        GLDS16(Bg + (size_t)64 * K + k0, &Bs[(size_t)(t + 256) * 8]);
        __syncthreads();   // drains vmcnt -> staged data visible
        short8 af[MF], bf[4];
#pragma unroll
        for (int i = 0; i < MF; ++i)
            af[i] = *(const short8*)&As[(wm + i * 16 + (lane & 15)) * 32 + (lane >> 4) * 8];
#pragma unroll
        for (int j = 0; j < 4; ++j)
            bf[j] = *(const short8*)&Bs[(wn + j * 16 + (lane & 15)) * 32 + (lane >> 4) * 8];
#pragma unroll
        for (int i = 0; i < MF; ++i)
#pragma unroll
            for (int j = 0; j < 4; ++j)
                acc[i][j] = __builtin_amdgcn_mfma_f32_16x16x32_bf16(af[i], bf[j], acc[i][j], 0, 0, 0);
        __syncthreads();   // protect LDS before next-iter staging
    }

    const int colb = n0 + wn + (lane & 15);
    const int rowb = m0 + wm + ((lane >> 4) * 4);
#pragma unroll
    for (int i = 0; i < MF; ++i) {
#pragma unroll
        for (int j = 0; j < 4; ++j) {
            const int col = colb + j * 16;
            const float bv = bias[col];
#pragma unroll
            for (int r = 0; r < 4; ++r) {
                const int row = rowb + i * 16 + r;
                float v = acc[i][j][r] + bv;
                if constexpr (ADD_POS) v += pos[(size_t)(row % LSEQ) * N + col];
                if constexpr (RES_F32) v += resf[(size_t)row * N + col];
                if constexpr (LEAKY)   v = v >= 0.f ? v : 0.01f * v;
                if constexpr (OUT_F32) ((float*)Cout)[(size_t)row * N + col] = v;
                else                   ((short*)Cout)[(size_t)row * N + col] = f2b(v);
            }
        }
    }
}

// ---------------- LayerNorm over E=768, input f32, outputs bf16 (+optional f32 copy) ----------------
__global__ __launch_bounds__(256)
void ln_kernel(const float* __restrict__ h, const float* __restrict__ g,
               const float* __restrict__ bbias, short* __restrict__ outb,
               float* __restrict__ outf)
{
    const int row = blockIdx.x;
    const float* x = h + (size_t)row * EMB;
    const int t = threadIdx.x;
    float v0 = x[t], v1 = x[t + 256], v2 = x[t + 512];
    float s  = v0 + v1 + v2;
    float ss = v0 * v0 + v1 * v1 + v2 * v2;
#pragma unroll
    for (int m = 1; m < 64; m <<= 1) {
        s  += __shfl_xor(s, m, 64);
        ss += __shfl_xor(ss, m, 64);
    }
    __shared__ float red[8];
    if ((t & 63) == 0) { red[t >> 6] = s; red[4 + (t >> 6)] = ss; }
    __syncthreads();
    float S  = red[0] + red[1] + red[2] + red[3];
    float SS = red[4] + red[5] + red[6] + red[7];
    float mean = S * (1.f / 768.f);
    float var  = SS * (1.f / 768.f) - mean * mean;
    float rstd = rsqrtf(var + 1e-5f);
    const size_t base = (size_t)row * EMB;
#pragma unroll
    for (int q = 0; q < 3; ++q) {
        int e = t + q * 256;
        float v = (q == 0 ? v0 : (q == 1 ? v1 : v2));
        float y = (v - mean) * rstd * g[e] + bbias[e];
        outb[base + e] = f2b(y);
        if (outf) outf[base + e] = y;
    }
}

// ---------------- per-layer K/V repack: kp[bh][l][d] (row-swizzled), vt[bh][d][l] (row-swizzled) ----
__global__ __launch_bounds__(256)
void repack_kv(const short* __restrict__ qkv, short* __restrict__ kp, short* __restrict__ vt)
{
    const int kt = blockIdx.x, bh = blockIdx.y;
    const int b = bh / 12, h = bh % 12;
    const int t = threadIdx.x;
#pragma unroll
    for (int i = 0; i < 2; ++i) {
        int flat = i * 256 + t;
        int key = flat >> 3, c = flat & 7;
        short8 vK = *(const short8*)(qkv + ((size_t)(b * LSEQ) + kt * 64 + key) * 2304 + 768 + h * 64 + c * 8);
        *(short8*)(kp + ((size_t)bh * LSEQ + kt * 64 + key) * 64 + 8 * (c ^ (key & 7))) = vK;
    }
    __shared__ short tile[64][65];
    const int tx = t & 63, ty = t >> 6;
#pragma unroll
    for (int r = 0; r < 16; ++r) {
        int k = ty * 16 + r;
        tile[k][tx] = qkv[((size_t)(b * LSEQ) + kt * 64 + k) * 2304 + 1536 + h * 64 + tx];
    }
    __syncthreads();
#pragma unroll
    for (int r = 0; r < 16; ++r) {
        int d = ty * 16 + r;
        vt[((size_t)bh * 64 + d) * LSEQ + kt * 64 + (tx ^ ((d & 7) << 3))] = tile[tx][d];
    }
}

// ---------------- MFMA flash attention. grid (9 qtiles, 96 bh), block 256 = 4 waves ----------------
__global__ __launch_bounds__(256)
void attn_mfma(const short* __restrict__ qkv, const short* __restrict__ kp,
               const short* __restrict__ vt, short* __restrict__ oout, int causal)
{
    const int qt = blockIdx.x, bh = blockIdx.y;
    const int b = bh / 12, h = bh % 12;
    const int t = threadIdx.x, lane = t & 63, w = t >> 6;

    __shared__ short Ks[64 * 64];
    __shared__ short Vs[64 * 64];
    __shared__ short Plds[4][16][72];

    const int nrow = lane & 15;
    const int kch  = (lane >> 4) * 8;
    const int swz  = (lane & 7) << 3;

    short8 aq[2];
    {
        const short* qrow = qkv + ((size_t)(b * LSEQ) + qt * 64 + w * 16 + nrow) * 2304 + h * 64 + kch;
        aq[0] = *(const short8*)qrow;
        aq[1] = *(const short8*)(qrow + 32);
    }

    float m[4], lsum[4];
    floatx4 oacc[4];
#pragma unroll
    for (int r = 0; r < 4; ++r) { m[r] = -3e38f; lsum[r] = 0.f; }
#pragma unroll
    for (int j = 0; j < 4; ++j) oacc[j] = (floatx4){0.f, 0.f, 0.f, 0.f};

    const int ktend = causal ? qt : 8;
    const short* ksrc = kp + ((size_t)bh * LSEQ) * 64;
    const short* vsrc = vt + ((size_t)bh * 64) * LSEQ;

    for (int kt = 0; kt <= ktend; ++kt) {
        __syncthreads();
        {
            const short* kt_src = ksrc + (size_t)(kt * 64) * 64;
            GLDS16(kt_src + (size_t)t * 8,          &Ks[(size_t)t * 8]);
            GLDS16(kt_src + (size_t)(t + 256) * 8,  &Ks[(size_t)(t + 256) * 8]);
            int f0 = t, f1 = t + 256;
            GLDS16(vsrc + (size_t)(f0 >> 3) * LSEQ + kt * 64 + (f0 & 7) * 8, &Vs[(size_t)f0 * 8]);
            GLDS16(vsrc + (size_t)(f1 >> 3) * LSEQ + kt * 64 + (f1 & 7) * 8, &Vs[(size_t)f1 * 8]);
        }
        __syncthreads();

        floatx4 sc[4];
#pragma unroll
        for (int j = 0; j < 4; ++j) sc[j] = (floatx4){0.f, 0.f, 0.f, 0.f};
#pragma unroll
        for (int s = 0; s < 2; ++s) {
#pragma unroll
            for (int j = 0; j < 4; ++j) {
                short8 bk = *(const short8*)&Ks[(16 * j + nrow) * 64 + ((kch + 32 * s) ^ swz)];
                sc[j] = __builtin_amdgcn_mfma_f32_16x16x32_bf16(aq[s], bk, sc[j], 0, 0, 0);
            }
        }
        float sv[4][4];
#pragma unroll
        for (int j = 0; j < 4; ++j)
#pragma unroll
            for (int r = 0; r < 4; ++r) {
                float v = sc[j][r] * 0.125f;
                if (causal && kt == qt) {
                    int key = kt * 64 + 16 * j + nrow;
                    int qr  = qt * 64 + w * 16 + (lane >> 4) * 4 + r;
                    if (key > qr) v = -1e12f;
                }
                sv[j][r] = v;
            }
#pragma unroll
        for (int r = 0; r < 4; ++r) {
            float tm = fmaxf(fmaxf(sv[0][r], sv[1][r]), fmaxf(sv[2][r], sv[3][r]));
            tm = fmaxf(tm, __shfl_xor(tm, 1, 64));
            tm = fmaxf(tm, __shfl_xor(tm, 2, 64));
            tm = fmaxf(tm, __shfl_xor(tm, 4, 64));
            tm = fmaxf(tm, __shfl_xor(tm, 8, 64));
            float nm = fmaxf(m[r], tm);
            float c  = __expf(m[r] - nm);
            m[r] = nm;
            float ps = 0.f;
#pragma unroll
            for (int j = 0; j < 4; ++j) {
                float p = __expf(sv[j][r] - nm);
                sv[j][r] = p;
                ps += p;
            }
            lsum[r] = lsum[r] * c + ps;
#pragma unroll
            for (int j = 0; j < 4; ++j) oacc[j][r] *= c;
        }
#pragma unroll
        for (int j = 0; j < 4; ++j)
#pragma unroll
            for (int r = 0; r < 4; ++r)
                Plds[w][(lane >> 4) * 4 + r][16 * j + nrow] = f2b(sv[j][r]);
        short8 ap[2];
#pragma unroll
        for (int s = 0; s < 2; ++s)
            ap[s] = *(const short8*)&Plds[w][nrow][kch + 32 * s];
#pragma unroll
        for (int s = 0; s < 2; ++s) {
#pragma unroll
            for (int j = 0; j < 4; ++j) {
                short8 bv = *(const short8*)&Vs[(16 * j + nrow) * 64 + ((kch + 32 * s) ^ swz)];
                oacc[j] = __builtin_amdgcn_mfma_f32_16x16x32_bf16(ap[s], bv, oacc[j], 0, 0, 0);
            }
        }
    }

    float inv[4];
#pragma unroll
    for (int r = 0; r < 4; ++r) {
        float L = lsum[r];
        L += __shfl_xor(L, 1, 64);
        L += __shfl_xor(L, 2, 64);
        L += __shfl_xor(L, 4, 64);
        L += __shfl_xor(L, 8, 64);
        inv[r] = 1.f / L;
    }
#pragma unroll
    for (int j = 0; j < 4; ++j)
#pragma unroll
        for (int r = 0; r < 4; ++r) {
            size_t lq = (size_t)qt * 64 + w * 16 + (lane >> 4) * 4 + r;
            oout[((size_t)bh * LSEQ + lq) * 64 + 16 * j + nrow] = f2b(oacc[j][r] * inv[r]);
        }
}

// ---------------- transposes ----------------
__global__ void transpose_f2b(const float* __restrict__ in, short* __restrict__ out,
                              int R, int C, long long ibs, long long obs)
{
    __shared__ float tile[32][33];
    const int b = blockIdx.z;
    const float* inb = in + (long long)b * ibs;
    short* outb = out + (long long)b * obs;
    const int r0 = blockIdx.y * 32, c0 = blockIdx.x * 32;
    const int tx = threadIdx.x, ty = threadIdx.y;
#pragma unroll
    for (int i = 0; i < 32; i += 8) tile[ty + i][tx] = inb[(size_t)(r0 + ty + i) * C + c0 + tx];
    __syncthreads();
#pragma unroll
    for (int i = 0; i < 32; i += 8) outb[(size_t)(c0 + ty + i) * R + r0 + tx] = f2b(tile[tx][ty + i]);
}

__global__ void transpose_f2f(const float* __restrict__ in, float* __restrict__ out,
                              int R, int C, long long ibs, long long obs)
{
    __shared__ float tile[32][33];
    const int b = blockIdx.z;
    const float* inb = in + (long long)b * ibs;
    float* outb = out + (long long)b * obs;
    const int r0 = blockIdx.y * 32, c0 = blockIdx.x * 32;
    const int tx = threadIdx.x, ty = threadIdx.y;
#pragma unroll
    for (int i = 0; i < 32; i += 8) tile[ty + i][tx] = inb[(size_t)(r0 + ty + i) * C + c0 + tx];
    __syncthreads();
#pragma unroll
    for (int i = 0; i < 32; i += 8) outb[(size_t)(c0 + ty + i) * R + r0 + tx] = tile[tx][ty + i];
}

// ---------------- misc small kernels ----------------
__global__ void concat_qkv_bias(const float* __restrict__ bq, const float* __restrict__ bk,
                                const float* __restrict__ bv, float* __restrict__ out)
{
    int i = blockIdx.x * 256 + threadIdx.x;
    int layer = i / 2304, j = i % 2304;
    float v;
    if (j < 768)       v = bq[layer * 768 + j];
    else if (j < 1536) v = bk[layer * 768 + j - 768];
    else               v = bv[layer * 768 + j - 1536];
    out[i] = v;
}

__global__ void im2col_kernel(const float* __restrict__ x, short* __restrict__ xcol)
{
    const size_t idx = (size_t)blockIdx.x * 256 + threadIdx.x;
    const int k = (int)(idx % 768);
    const size_t m = idx / 768;
    const int c  = k >> 8;
    const int ky = (k >> 4) & 15;
    const int kx = k & 15;
    const int b  = (int)(m / 576);
    const int l  = (int)(m % 576);
    const int ph = l / 24, pw = l % 24;
    xcol[idx] = f2b(x[((size_t)(b * 3 + c) * 384 + ph * 16 + ky) * 384 + pw * 16 + kx]);
}

__global__ void cast_f32_b16(const float* __restrict__ in, short* __restrict__ out, int n)
{
    int i = blockIdx.x * 256 + threadIdx.x;
    if (i < n) out[i] = f2b(in[i]);
}

// ---------------- host launcher ----------------
extern "C" void kernel_launch(void* const* d_in, const int* in_sizes, int n_in,
                              void* d_out, int out_size, void* d_ws, size_t ws_size,
                              hipStream_t stream)
{
    const float* x      = (const float*)d_in[0];
    const float* conv_w = (const float*)d_in[1];
    const float* conv_b = (const float*)d_in[2];
    const float* pos    = (const float*)d_in[3];
    const float* ln0_s  = (const float*)d_in[4];
    const float* ln0_b  = (const float*)d_in[5];
    const float* Wq     = (const float*)d_in[6];
    const float* bq     = (const float*)d_in[7];
    const float* Wk     = (const float*)d_in[8];
    const float* bk     = (const float*)d_in[9];
    const float* Wv     = (const float*)d_in[10];
    const float* bv     = (const float*)d_in[11];
    const float* Wo     = (const float*)d_in[12];
    const float* bo     = (const float*)d_in[13];
    const float* ln1_s  = (const float*)d_in[14];
    const float* ln1_b  = (const float*)d_in[15];
    const float* W1     = (const float*)d_in[16];
    const float* b1     = (const float*)d_in[17];
    const float* W2     = (const float*)d_in[18];
    const float* b2     = (const float*)d_in[19];
    const float* proj_w = (const float*)d_in[20];
    const float* proj_b = (const float*)d_in[21];

    char* ws = (char*)d_ws;
    short* qkvT  = (short*)(ws);                    // [8][2304][768] bf16
    short* woT   = (short*)(ws + 28311552);         // [8][768][768]
    short* w1T   = (short*)(ws + 37748736);         // [8][3072][768]
    short* w2T   = (short*)(ws + 75497472);         // [8][768][3072]
    short* projT = (short*)(ws + 113246208);        // [768][768]
    float* qkvb  = (float*)(ws + 114425856);        // [8][2304] f32
    short* tmpA  = (short*)(ws + 114499584);        // xcol / m1 bf16 [4608][3072]; kp/vt overlay; yf f32
    float* h     = (float*)(ws + 142811136);        // residual stream f32 [4608][768]
    short* xn    = (short*)(ws + 156966912);        // LN0 out bf16; hb at end
    short* xrb   = (short*)(ws + 164044800);        // LN1 out bf16
    float* xrf   = (float*)(ws + 171122688);        // LN1 out f32
    short* qkv   = (short*)(ws + 185278464);        // [4608][2304] bf16
    short* o     = (short*)(ws + 206512128);        // attn out (scrambled) bf16
    short* convB = (short*)(ws + 213590016);        // conv_w cast bf16 [768][768]

    short* kp = tmpA;                               // [96][576][64] bf16
    short* vt = tmpA + 3538944;                     // [96][64][576] bf16

    dim3 tb(32, 8);
    transpose_f2b<<<dim3(24, 24, 8), tb, 0, stream>>>(Wq, qkvT,           768, 768, 589824, 1769472);
    transpose_f2b<<<dim3(24, 24, 8), tb, 0, stream>>>(Wk, qkvT + 589824,  768, 768, 589824, 1769472);
    transpose_f2b<<<dim3(24, 24, 8), tb, 0, stream>>>(Wv, qkvT + 1179648, 768, 768, 589824, 1769472);
    transpose_f2b<<<dim3(24, 24, 8), tb, 0, stream>>>(Wo, woT,            768, 768, 589824, 589824);
    transpose_f2b<<<dim3(96, 24, 8), tb, 0, stream>>>(W1, w1T,            768, 3072, 2359296, 2359296);
    transpose_f2b<<<dim3(24, 96, 8), tb, 0, stream>>>(W2, w2T,            3072, 768, 2359296, 2359296);
    transpose_f2b<<<dim3(24, 24, 1), tb, 0, stream>>>(proj_w, projT,      768, 768, 0, 0);
    cast_f32_b16<<<2304, 256, 0, stream>>>(conv_w, convB, 589824);
    concat_qkv_bias<<<72, 256, 0, stream>>>(bq, bk, bv, qkvb);

    // patch embed: im2col + GEMM(convB as Bt) + conv_b + pos  -> h (f32)
    im2col_kernel<<<13824, 256, 0, stream>>>(x, tmpA);
    gemm_bt<2, true, false, false, true><<<dim3(6, 72), 256, 0, stream>>>(
        tmpA, convB, conv_b, pos, nullptr, h, 768, 768);

    for (int i = 0; i < NLAYERS; ++i) {
        ln_kernel<<<4608, 256, 0, stream>>>(h, ln0_s + i * 768, ln0_b + i * 768, xn, nullptr);
        gemm_bt<4, false, false, false, false><<<dim3(18, 36), 256, 0, stream>>>(
            xn, qkvT + (size_t)i * 1769472, qkvb + i * 2304, nullptr, nullptr, qkv, 2304, 768);
        repack_kv<<<dim3(9, 96), 256, 0, stream>>>(qkv, kp, vt);
        attn_mfma<<<dim3(9, 96), 256, 0, stream>>>(qkv, kp, vt, o, i == 0 ? 1 : 0);
        gemm_bt<2, false, true, false, true><<<dim3(6, 72), 256, 0, stream>>>(
            o, woT + (size_t)i * 589824, bo + i * 768, nullptr, h, h, 768, 768);
        ln_kernel<<<4608, 256, 0, stream>>>(h, ln1_s + i * 768, ln1_b + i * 768, xrb, xrf);
        gemm_bt<4, false, false, true, false><<<dim3(24, 36), 256, 0, stream>>>(
            xrb, w1T + (size_t)i * 2359296, b1 + i * 3072, nullptr, nullptr, tmpA, 3072, 768);
        gemm_bt<2, false, true, false, true><<<dim3(6, 72), 256, 0, stream>>>(
            tmpA, w2T + (size_t)i * 2359296, b2 + i * 768, nullptr, xrf, h, 768, 3072);
    }

    // final projection + output scramble (B, L, CPP) -> (B, CPP, L) flat
    short* hb = xn;
    float* yf = (float*)tmpA;
    cast_f32_b16<<<13824, 256, 0, stream>>>(h, hb, 4608 * 768);
    gemm_bt<2, false, false, false, true><<<dim3(6, 72), 256, 0, stream>>>(
        hb, projT, proj_b, nullptr, nullptr, yf, 768, 768);
    transpose_f2f<<<dim3(24, 18, 8), tb, 0, stream>>>(yf, (float*)d_out, 576, 768, 442368, 442368);
}

// Round 8
// 1695.128 us; speedup vs baseline: 3.6413x; 1.0596x over previous
//
#include <hip/hip_runtime.h>
#include <hip/hip_bf16.h>
#include <stdint.h>

#define NLAYERS 8
#define LSEQ 576
#define EMB 768
#define NHEAD 12
#define HDIM 64
#define FFDIM 3072
#define BLROWS 4608   // B*L

typedef __attribute__((ext_vector_type(8))) short short8;
typedef __attribute__((ext_vector_type(4))) float floatx4;

__device__ __forceinline__ float b2f(short s) {
    union { float f; uint32_t u; } x; x.u = ((uint32_t)(uint16_t)s) << 16; return x.f;
}
__device__ __forceinline__ short f2b(float f) {
    union { float f; uint32_t u; } x; x.f = f;
    uint32_t r = x.u + 0x7fffu + ((x.u >> 16) & 1u);
    return (short)(r >> 16);
}

#define GLDS16(gp, lp) __builtin_amdgcn_global_load_lds( \
    (const __attribute__((address_space(1))) void*)(gp), \
    (__attribute__((address_space(3))) void*)(lp), 16, 0, 0)

// bijective XCD-chunked remap (m204)
__device__ __forceinline__ void xcd_remap(int& bx, int& by) {
    const int gx = gridDim.x;
    const int n  = gx * gridDim.y;
    const int orig = by * gx + bx;
    const int q = n >> 3, r = n & 7;
    const int xcd = orig & 7;
    const int wgid = (xcd < r ? xcd * (q + 1) : r * (q + 1) + (xcd - r) * q) + (orig >> 3);
    bx = wgid % gx;
    by = wgid / gx;
}

// ---------------- GEMM: C[M,N] = A[M,K](bf16) * Bt[N,K]^T (bf16) + epilogue ----------------
// 64x128 tile, BK=64, double-buffered LDS, 1 barrier/K-step, prefetch-next-before-compute.
// LDS XOR-swizzle (T2, rule 21): linear global_load_lds dest; global source chunk ^= (row&7);
// reads apply the same XOR -> bank conflicts ~2-way (free).
// block = 256 (4 waves, 2x2 of 32x64 per wave)
template<bool ADD_POS, bool RES_F32, bool LEAKY, bool OUT_F32>
__global__ __launch_bounds__(256)
void gemm_bt(const short* __restrict__ A, const short* __restrict__ Bt,
             const float* __restrict__ bias, const float* __restrict__ pos,
             const float* __restrict__ resf, void* __restrict__ Cout,
             int N, int K)
{
    __shared__ short As[2 * 64 * 64];     // 16 KB
    __shared__ short Bs[2 * 128 * 64];    // 32 KB
    int bx = blockIdx.x, by = blockIdx.y;
    xcd_remap(bx, by);
    const int t    = threadIdx.x;
    const int lane = t & 63;
    const int w    = t >> 6;
    const int m0   = by * 64;
    const int n0   = bx * 128;
    const int wm   = (w >> 1) * 32;
    const int wn   = (w & 1) * 64;

    floatx4 acc[2][4];
#pragma unroll
    for (int i = 0; i < 2; ++i)
#pragma unroll
        for (int j = 0; j < 4; ++j)
            acc[i][j] = (floatx4){0.f, 0.f, 0.f, 0.f};

    // staging: flat f = t + i*256 -> row = f>>3 (64/128 rows), chunk = f&7 (8 x 16B = 64 bf16)
    const int srow = t >> 3;
    const int sch  = t & 7;

    const short* Ag = A  + (size_t)m0 * K;
    const short* Bg = Bt + (size_t)n0 * K;

#define STAGE(buf, k0)                                                              \
    {                                                                               \
        _Pragma("unroll")                                                           \
        for (int i = 0; i < 2; ++i) {                                               \
            int row = srow + i * 32;                                                \
            GLDS16(Ag + (size_t)row * K + (k0) + ((sch ^ (row & 7)) << 3),          \
                   &As[(buf) * 4096 + (size_t)(t + i * 256) * 8]);                  \
        }                                                                           \
        _Pragma("unroll")                                                           \
        for (int i = 0; i < 4; ++i) {                                               \
            int row = srow + i * 32;                                                \
            GLDS16(Bg + (size_t)row * K + (k0) + ((sch ^ (row & 7)) << 3),          \
                   &Bs[(buf) * 8192 + (size_t)(t + i * 256) * 8]);                  \
        }                                                                           \
    }

    STAGE(0, 0);
    __syncthreads();
    int cur = 0;
    for (int k0 = 0; k0 < K; k0 += 64) {
        if (k0 + 64 < K) STAGE(cur ^ 1, k0 + 64);
#pragma unroll
        for (int ks = 0; ks < 2; ++ks) {
            short8 af[2], bf[4];
#pragma unroll
            for (int i = 0; i < 2; ++i) {
                int row = wm + i * 16 + (lane & 15);
                int ch  = (ks * 4 + (lane >> 4)) ^ (row & 7);
                af[i] = *(const short8*)&As[cur * 4096 + row * 64 + ch * 8];
            }
#pragma unroll
            for (int j = 0; j < 4; ++j) {
                int row = wn + j * 16 + (lane & 15);
                int ch  = (ks * 4 + (lane >> 4)) ^ (row & 7);
                bf[j] = *(const short8*)&Bs[cur * 8192 + row * 64 + ch * 8];
            }
#pragma unroll
            for (int i = 0; i < 2; ++i)
#pragma unroll
                for (int j = 0; j < 4; ++j)
                    acc[i][j] = __builtin_amdgcn_mfma_f32_16x16x32_bf16(af[i], bf[j], acc[i][j], 0, 0, 0);
        }
        __syncthreads();   // drains vmcnt (prefetch landed) + protects LDS reuse
        cur ^= 1;
    }
#undef STAGE

    const int colb = n0 + wn + (lane & 15);
    const int rowb = m0 + wm + ((lane >> 4) * 4);
#pragma unroll
    for (int i = 0; i < 2; ++i) {
#pragma unroll
        for (int j = 0; j < 4; ++j) {
            const int col = colb + j * 16;
            const float bv = bias[col];
#pragma unroll
            for (int r = 0; r < 4; ++r) {
                const int row = rowb + i * 16 + r;
                float v = acc[i][j][r] + bv;
                if constexpr (ADD_POS) v += pos[(size_t)(row % LSEQ) * N + col];
                if constexpr (RES_F32) v += resf[(size_t)row * N + col];
                if constexpr (LEAKY)   v = v >= 0.f ? v : 0.01f * v;
                if constexpr (OUT_F32) ((float*)Cout)[(size_t)row * N + col] = v;
                else                   ((short*)Cout)[(size_t)row * N + col] = f2b(v);
            }
        }
    }
}

// ---------------- LayerNorm over E=768, input f32, outputs bf16 (+optional f32 copy) ----------------
__global__ __launch_bounds__(256)
void ln_kernel(const float* __restrict__ h, const float* __restrict__ g,
               const float* __restrict__ bbias, short* __restrict__ outb,
               float* __restrict__ outf)
{
    const int row = blockIdx.x;
    const float* x = h + (size_t)row * EMB;
    const int t = threadIdx.x;
    float v0 = x[t], v1 = x[t + 256], v2 = x[t + 512];
    float s  = v0 + v1 + v2;
    float ss = v0 * v0 + v1 * v1 + v2 * v2;
#pragma unroll
    for (int m = 1; m < 64; m <<= 1) {
        s  += __shfl_xor(s, m, 64);
        ss += __shfl_xor(ss, m, 64);
    }
    __shared__ float red[8];
    if ((t & 63) == 0) { red[t >> 6] = s; red[4 + (t >> 6)] = ss; }
    __syncthreads();
    float S  = red[0] + red[1] + red[2] + red[3];
    float SS = red[4] + red[5] + red[6] + red[7];
    float mean = S * (1.f / 768.f);
    float var  = SS * (1.f / 768.f) - mean * mean;
    float rstd = rsqrtf(var + 1e-5f);
    const size_t base = (size_t)row * EMB;
#pragma unroll
    for (int q = 0; q < 3; ++q) {
        int e = t + q * 256;
        float v = (q == 0 ? v0 : (q == 1 ? v1 : v2));
        float y = (v - mean) * rstd * g[e] + bbias[e];
        outb[base + e] = f2b(y);
        if (outf) outf[base + e] = y;
    }
}

// ---------------- per-layer K/V repack: kp[bh][l][d] (row-swizzled), vt[bh][d][l] (row-swizzled) ----
__global__ __launch_bounds__(256)
void repack_kv(const short* __restrict__ qkv, short* __restrict__ kp, short* __restrict__ vt)
{
    const int kt = blockIdx.x, bh = blockIdx.y;
    const int b = bh / 12, h = bh % 12;
    const int t = threadIdx.x;
#pragma unroll
    for (int i = 0; i < 2; ++i) {
        int flat = i * 256 + t;
        int key = flat >> 3, c = flat & 7;
        short8 vK = *(const short8*)(qkv + ((size_t)(b * LSEQ) + kt * 64 + key) * 2304 + 768 + h * 64 + c * 8);
        *(short8*)(kp + ((size_t)bh * LSEQ + kt * 64 + key) * 64 + 8 * (c ^ (key & 7))) = vK;
    }
    __shared__ short tile[64][65];
    const int tx = t & 63, ty = t >> 6;
#pragma unroll
    for (int r = 0; r < 16; ++r) {
        int k = ty * 16 + r;
        tile[k][tx] = qkv[((size_t)(b * LSEQ) + kt * 64 + k) * 2304 + 1536 + h * 64 + tx];
    }
    __syncthreads();
#pragma unroll
    for (int r = 0; r < 16; ++r) {
        int d = ty * 16 + r;
        vt[((size_t)bh * 64 + d) * LSEQ + kt * 64 + (tx ^ ((d & 7) << 3))] = tile[tx][d];
    }
}

// ---------------- MFMA flash attention. grid (9 qtiles, 96 bh), block 256 = 4 waves ----------------
__global__ __launch_bounds__(256)
void attn_mfma(const short* __restrict__ qkv, const short* __restrict__ kp,
               const short* __restrict__ vt, short* __restrict__ oout, int causal)
{
    const int qt = blockIdx.x, bh = blockIdx.y;
    const int b = bh / 12, h = bh % 12;
    const int t = threadIdx.x, lane = t & 63, w = t >> 6;

    __shared__ short Ks[64 * 64];
    __shared__ short Vs[64 * 64];
    __shared__ short Plds[4][16][72];

    const int nrow = lane & 15;
    const int kch  = (lane >> 4) * 8;
    const int swz  = (lane & 7) << 3;

    short8 aq[2];
    {
        const short* qrow = qkv + ((size_t)(b * LSEQ) + qt * 64 + w * 16 + nrow) * 2304 + h * 64 + kch;
        aq[0] = *(const short8*)qrow;
        aq[1] = *(const short8*)(qrow + 32);
    }

    float m[4], lsum[4];
    floatx4 oacc[4];
#pragma unroll
    for (int r = 0; r < 4; ++r) { m[r] = -3e38f; lsum[r] = 0.f; }
#pragma unroll
    for (int j = 0; j < 4; ++j) oacc[j] = (floatx4){0.f, 0.f, 0.f, 0.f};

    const int ktend = causal ? qt : 8;
    const short* ksrc = kp + ((size_t)bh * LSEQ) * 64;
    const short* vsrc = vt + ((size_t)bh * 64) * LSEQ;

    for (int kt = 0; kt <= ktend; ++kt) {
        __syncthreads();
        {
            const short* kt_src = ksrc + (size_t)(kt * 64) * 64;
            GLDS16(kt_src + (size_t)t * 8,          &Ks[(size_t)t * 8]);
            GLDS16(kt_src + (size_t)(t + 256) * 8,  &Ks[(size_t)(t + 256) * 8]);
            int f0 = t, f1 = t + 256;
            GLDS16(vsrc + (size_t)(f0 >> 3) * LSEQ + kt * 64 + (f0 & 7) * 8, &Vs[(size_t)f0 * 8]);
            GLDS16(vsrc + (size_t)(f1 >> 3) * LSEQ + kt * 64 + (f1 & 7) * 8, &Vs[(size_t)f1 * 8]);
        }
        __syncthreads();

        floatx4 sc[4];
#pragma unroll
        for (int j = 0; j < 4; ++j) sc[j] = (floatx4){0.f, 0.f, 0.f, 0.f};
#pragma unroll
        for (int s = 0; s < 2; ++s) {
#pragma unroll
            for (int j = 0; j < 4; ++j) {
                short8 bk = *(const short8*)&Ks[(16 * j + nrow) * 64 + ((kch + 32 * s) ^ swz)];
                sc[j] = __builtin_amdgcn_mfma_f32_16x16x32_bf16(aq[s], bk, sc[j], 0, 0, 0);
            }
        }
        float sv[4][4];
#pragma unroll
        for (int j = 0; j < 4; ++j)
#pragma unroll
            for (int r = 0; r < 4; ++r) {
                float v = sc[j][r] * 0.125f;
                if (causal && kt == qt) {
                    int key = kt * 64 + 16 * j + nrow;
                    int qr  = qt * 64 + w * 16 + (lane >> 4) * 4 + r;
                    if (key > qr) v = -1e12f;
                }
                sv[j][r] = v;
            }
#pragma unroll
        for (int r = 0; r < 4; ++r) {
            float tm = fmaxf(fmaxf(sv[0][r], sv[1][r]), fmaxf(sv[2][r], sv[3][r]));
            tm = fmaxf(tm, __shfl_xor(tm, 1, 64));
            tm = fmaxf(tm, __shfl_xor(tm, 2, 64));
            tm = fmaxf(tm, __shfl_xor(tm, 4, 64));
            tm = fmaxf(tm, __shfl_xor(tm, 8, 64));
            float nm = fmaxf(m[r], tm);
            float c  = __expf(m[r] - nm);
            m[r] = nm;
            float ps = 0.f;
#pragma unroll
            for (int j = 0; j < 4; ++j) {
                float p = __expf(sv[j][r] - nm);
                sv[j][r] = p;
                ps += p;
            }
            lsum[r] = lsum[r] * c + ps;
#pragma unroll
            for (int j = 0; j < 4; ++j) oacc[j][r] *= c;
        }
#pragma unroll
        for (int j = 0; j < 4; ++j)
#pragma unroll
            for (int r = 0; r < 4; ++r)
                Plds[w][(lane >> 4) * 4 + r][16 * j + nrow] = f2b(sv[j][r]);
        short8 ap[2];
#pragma unroll
        for (int s = 0; s < 2; ++s)
            ap[s] = *(const short8*)&Plds[w][nrow][kch + 32 * s];
#pragma unroll
        for (int s = 0; s < 2; ++s) {
#pragma unroll
            for (int j = 0; j < 4; ++j) {
                short8 bv = *(const short8*)&Vs[(16 * j + nrow) * 64 + ((kch + 32 * s) ^ swz)];
                oacc[j] = __builtin_amdgcn_mfma_f32_16x16x32_bf16(ap[s], bv, oacc[j], 0, 0, 0);
            }
        }
    }

    float inv[4];
#pragma unroll
    for (int r = 0; r < 4; ++r) {
        float L = lsum[r];
        L += __shfl_xor(L, 1, 64);
        L += __shfl_xor(L, 2, 64);
        L += __shfl_xor(L, 4, 64);
        L += __shfl_xor(L, 8, 64);
        inv[r] = 1.f / L;
    }
#pragma unroll
    for (int j = 0; j < 4; ++j)
#pragma unroll
        for (int r = 0; r < 4; ++r) {
            size_t lq = (size_t)qt * 64 + w * 16 + (lane >> 4) * 4 + r;
            oout[((size_t)bh * LSEQ + lq) * 64 + 16 * j + nrow] = f2b(oacc[j][r] * inv[r]);
        }
}

// ---------------- transposes ----------------
__global__ void transpose_f2b(const float* __restrict__ in, short* __restrict__ out,
                              int R, int C, long long ibs, long long obs)
{
    __shared__ float tile[32][33];
    const int b = blockIdx.z;
    const float* inb = in + (long long)b * ibs;
    short* outb = out + (long long)b * obs;
    const int r0 = blockIdx.y * 32, c0 = blockIdx.x * 32;
    const int tx = threadIdx.x, ty = threadIdx.y;
#pragma unroll
    for (int i = 0; i < 32; i += 8) tile[ty + i][tx] = inb[(size_t)(r0 + ty + i) * C + c0 + tx];
    __syncthreads();
#pragma unroll
    for (int i = 0; i < 32; i += 8) outb[(size_t)(c0 + ty + i) * R + r0 + tx] = f2b(tile[tx][ty + i]);
}

__global__ void transpose_f2f(const float* __restrict__ in, float* __restrict__ out,
                              int R, int C, long long ibs, long long obs)
{
    __shared__ float tile[32][33];
    const int b = blockIdx.z;
    const float* inb = in + (long long)b * ibs;
    float* outb = out + (long long)b * obs;
    const int r0 = blockIdx.y * 32, c0 = blockIdx.x * 32;
    const int tx = threadIdx.x, ty = threadIdx.y;
#pragma unroll
    for (int i = 0; i < 32; i += 8) tile[ty + i][tx] = inb[(size_t)(r0 + ty + i) * C + c0 + tx];
    __syncthreads();
#pragma unroll
    for (int i = 0; i < 32; i += 8) outb[(size_t)(c0 + ty + i) * R + r0 + tx] = tile[tx][ty + i];
}

// ---------------- misc small kernels ----------------
__global__ void concat_qkv_bias(const float* __restrict__ bq, const float* __restrict__ bk,
                                const float* __restrict__ bv, float* __restrict__ out)
{
    int i = blockIdx.x * 256 + threadIdx.x;
    int layer = i / 2304, j = i % 2304;
    float v;
    if (j < 768)       v = bq[layer * 768 + j];
    else if (j < 1536) v = bk[layer * 768 + j - 768];
    else               v = bv[layer * 768 + j - 1536];
    out[i] = v;
}

__global__ void im2col_kernel(const float* __restrict__ x, short* __restrict__ xcol)
{
    const size_t idx = (size_t)blockIdx.x * 256 + threadIdx.x;
    const int k = (int)(idx % 768);
    const size_t m = idx / 768;
    const int c  = k >> 8;
    const int ky = (k >> 4) & 15;
    const int kx = k & 15;
    const int b  = (int)(m / 576);
    const int l  = (int)(m % 576);
    const int ph = l / 24, pw = l % 24;
    xcol[idx] = f2b(x[((size_t)(b * 3 + c) * 384 + ph * 16 + ky) * 384 + pw * 16 + kx]);
}

__global__ void cast_f32_b16(const float* __restrict__ in, short* __restrict__ out, int n)
{
    int i = blockIdx.x * 256 + threadIdx.x;
    if (i < n) out[i] = f2b(in[i]);
}

// ---------------- host launcher ----------------
extern "C" void kernel_launch(void* const* d_in, const int* in_sizes, int n_in,
                              void* d_out, int out_size, void* d_ws, size_t ws_size,
                              hipStream_t stream)
{
    const float* x      = (const float*)d_in[0];
    const float* conv_w = (const float*)d_in[1];
    const float* conv_b = (const float*)d_in[2];
    const float* pos    = (const float*)d_in[3];
    const float* ln0_s  = (const float*)d_in[4];
    const float* ln0_b  = (const float*)d_in[5];
    const float* Wq     = (const float*)d_in[6];
    const float* bq     = (const float*)d_in[7];
    const float* Wk     = (const float*)d_in[8];
    const float* bk     = (const float*)d_in[9];
    const float* Wv     = (const float*)d_in[10];
    const float* bv     = (const float*)d_in[11];
    const float* Wo     = (const float*)d_in[12];
    const float* bo     = (const float*)d_in[13];
    const float* ln1_s  = (const float*)d_in[14];
    const float* ln1_b  = (const float*)d_in[15];
    const float* W1     = (const float*)d_in[16];
    const float* b1     = (const float*)d_in[17];
    const float* W2     = (const float*)d_in[18];
    const float* b2     = (const float*)d_in[19];
    const float* proj_w = (const float*)d_in[20];
    const float* proj_b = (const float*)d_in[21];

    char* ws = (char*)d_ws;
    short* qkvT  = (short*)(ws);                    // [8][2304][768] bf16
    short* woT   = (short*)(ws + 28311552);         // [8][768][768]
    short* w1T   = (short*)(ws + 37748736);         // [8][3072][768]
    short* w2T   = (short*)(ws + 75497472);         // [8][768][3072]
    short* projT = (short*)(ws + 113246208);        // [768][768]
    float* qkvb  = (float*)(ws + 114425856);        // [8][2304] f32
    short* tmpA  = (short*)(ws + 114499584);        // xcol / m1 bf16 [4608][3072]; kp/vt overlay; yf f32
    float* h     = (float*)(ws + 142811136);        // residual stream f32 [4608][768]
    short* xn    = (short*)(ws + 156966912);        // LN0 out bf16; hb at end
    short* xrb   = (short*)(ws + 164044800);        // LN1 out bf16
    float* xrf   = (float*)(ws + 171122688);        // LN1 out f32
    short* qkv   = (short*)(ws + 185278464);        // [4608][2304] bf16
    short* o     = (short*)(ws + 206512128);        // attn out (scrambled) bf16
    short* convB = (short*)(ws + 213590016);        // conv_w cast bf16 [768][768]

    short* kp = tmpA;                               // [96][576][64] bf16
    short* vt = tmpA + 3538944;                     // [96][64][576] bf16

    dim3 tb(32, 8);
    transpose_f2b<<<dim3(24, 24, 8), tb, 0, stream>>>(Wq, qkvT,           768, 768, 589824, 1769472);
    transpose_f2b<<<dim3(24, 24, 8), tb, 0, stream>>>(Wk, qkvT + 589824,  768, 768, 589824, 1769472);
    transpose_f2b<<<dim3(24, 24, 8), tb, 0, stream>>>(Wv, qkvT + 1179648, 768, 768, 589824, 1769472);
    transpose_f2b<<<dim3(24, 24, 8), tb, 0, stream>>>(Wo, woT,            768, 768, 589824, 589824);
    transpose_f2b<<<dim3(96, 24, 8), tb, 0, stream>>>(W1, w1T,            768, 3072, 2359296, 2359296);
    transpose_f2b<<<dim3(24, 96, 8), tb, 0, stream>>>(W2, w2T,            3072, 768, 2359296, 2359296);
    transpose_f2b<<<dim3(24, 24, 1), tb, 0, stream>>>(proj_w, projT,      768, 768, 0, 0);
    cast_f32_b16<<<2304, 256, 0, stream>>>(conv_w, convB, 589824);
    concat_qkv_bias<<<72, 256, 0, stream>>>(bq, bk, bv, qkvb);

    // patch embed: im2col + GEMM(convB as Bt) + conv_b + pos  -> h (f32)
    im2col_kernel<<<13824, 256, 0, stream>>>(x, tmpA);
    gemm_bt<true, false, false, true><<<dim3(6, 72), 256, 0, stream>>>(
        tmpA, convB, conv_b, pos, nullptr, h, 768, 768);

    for (int i = 0; i < NLAYERS; ++i) {
        ln_kernel<<<4608, 256, 0, stream>>>(h, ln0_s + i * 768, ln0_b + i * 768, xn, nullptr);
        gemm_bt<false, false, false, false><<<dim3(18, 72), 256, 0, stream>>>(
            xn, qkvT + (size_t)i * 1769472, qkvb + i * 2304, nullptr, nullptr, qkv, 2304, 768);
        repack_kv<<<dim3(9, 96), 256, 0, stream>>>(qkv, kp, vt);
        attn_mfma<<<dim3(9, 96), 256, 0, stream>>>(qkv, kp, vt, o, i == 0 ? 1 : 0);
        gemm_bt<false, true, false, true><<<dim3(6, 72), 256, 0, stream>>>(
            o, woT + (size_t)i * 589824, bo + i * 768, nullptr, h, h, 768, 768);
        ln_kernel<<<4608, 256, 0, stream>>>(h, ln1_s + i * 768, ln1_b + i * 768, xrb, xrf);
        gemm_bt<false, false, true, false><<<dim3(24, 72), 256, 0, stream>>>(
            xrb, w1T + (size_t)i * 2359296, b1 + i * 3072, nullptr, nullptr, tmpA, 3072, 768);
        gemm_bt<false, true, false, true><<<dim3(6, 72), 256, 0, stream>>>(
            tmpA, w2T + (size_t)i * 2359296, b2 + i * 768, nullptr, xrf, h, 768, 3072);
    }

    // final projection + output scramble (B, L, CPP) -> (B, CPP, L) flat
    short* hb = xn;
    float* yf = (float*)tmpA;
    cast_f32_b16<<<13824, 256, 0, stream>>>(h, hb, 4608 * 768);
    gemm_bt<false, false, false, true><<<dim3(6, 72), 256, 0, stream>>>(
        hb, projT, proj_b, nullptr, nullptr, yf, 768, 768);
    transpose_f2f<<<dim3(24, 18, 8), tb, 0, stream>>>(yf, (float*)d_out, 576, 768, 442368, 442368);
}

// Round 9
// 1640.419 us; speedup vs baseline: 3.7627x; 1.0334x over previous
//
#include <hip/hip_runtime.h>
#include <hip/hip_bf16.h>
#include <stdint.h>

#define NLAYERS 8
#define LSEQ 576
#define EMB 768
#define NHEAD 12
#define HDIM 64
#define FFDIM 3072
#define BLROWS 4608   // B*L

typedef __attribute__((ext_vector_type(8))) short short8;
typedef __attribute__((ext_vector_type(4))) float floatx4;

__device__ __forceinline__ float b2f(short s) {
    union { float f; uint32_t u; } x; x.u = ((uint32_t)(uint16_t)s) << 16; return x.f;
}
__device__ __forceinline__ short f2b(float f) {
    union { float f; uint32_t u; } x; x.f = f;
    uint32_t r = x.u + 0x7fffu + ((x.u >> 16) & 1u);
    return (short)(r >> 16);
}

#define GLDS16(gp, lp) __builtin_amdgcn_global_load_lds( \
    (const __attribute__((address_space(1))) void*)(gp), \
    (__attribute__((address_space(3))) void*)(lp), 16, 0, 0)

// bijective XCD-chunked remap (m204)
__device__ __forceinline__ void xcd_remap(int& bx, int& by) {
    const int gx = gridDim.x;
    const int n  = gx * gridDim.y;
    const int orig = by * gx + bx;
    const int q = n >> 3, r = n & 7;
    const int xcd = orig & 7;
    const int wgid = (xcd < r ? xcd * (q + 1) : r * (q + 1) + (xcd - r) * q) + (orig >> 3);
    bx = wgid % gx;
    by = wgid / gx;
}

// ---------------- GEMM: C[M,N] = A[M,K](bf16) * Bt[N,K]^T (bf16) + epilogue ----------------
// 64x128 tile, BK=64, DEPTH-buffered LDS (T2 swizzle via pre-swizzled global source).
// DEPTH=2: stage-next -> compute -> __syncthreads (full drain).
// DEPTH=3: stage t+2 -> compute t -> s_waitcnt vmcnt(6) (counted, T4) -> raw barrier.
// RES: 0 none, 1 f32 residual, 2 bf16 residual.
template<int DEPTH, int RES, bool ADD_POS, bool LEAKY, bool OUT_F32>
__global__ __launch_bounds__(256)
void gemm_bt(const short* __restrict__ A, const short* __restrict__ Bt,
             const float* __restrict__ bias, const float* __restrict__ pos,
             const void* __restrict__ res, void* __restrict__ Cout,
             int N, int K)
{
    __shared__ short As[DEPTH * 64 * 64];
    __shared__ short Bs[DEPTH * 128 * 64];
    int bx = blockIdx.x, by = blockIdx.y;
    xcd_remap(bx, by);
    const int t    = threadIdx.x;
    const int lane = t & 63;
    const int w    = t >> 6;
    const int m0   = by * 64;
    const int n0   = bx * 128;
    const int wm   = (w >> 1) * 32;
    const int wn   = (w & 1) * 64;

    floatx4 acc[2][4];
#pragma unroll
    for (int i = 0; i < 2; ++i)
#pragma unroll
        for (int j = 0; j < 4; ++j)
            acc[i][j] = (floatx4){0.f, 0.f, 0.f, 0.f};

    const int srow = t >> 3;
    const int sch  = t & 7;
    const short* Ag = A  + (size_t)m0 * K;
    const short* Bg = Bt + (size_t)n0 * K;
    const int nt = K >> 6;

#define STAGE(buf, k0)                                                              \
    {                                                                               \
        _Pragma("unroll")                                                           \
        for (int i = 0; i < 2; ++i) {                                               \
            int row = srow + i * 32;                                                \
            GLDS16(Ag + (size_t)row * K + (k0) + ((sch ^ (row & 7)) << 3),          \
                   &As[(buf) * 4096 + (size_t)(t + i * 256) * 8]);                  \
        }                                                                           \
        _Pragma("unroll")                                                           \
        for (int i = 0; i < 4; ++i) {                                               \
            int row = srow + i * 32;                                                \
            GLDS16(Bg + (size_t)row * K + (k0) + ((sch ^ (row & 7)) << 3),          \
                   &Bs[(buf) * 8192 + (size_t)(t + i * 256) * 8]);                  \
        }                                                                           \
    }

#define COMPUTE(buf)                                                                \
    {                                                                               \
        _Pragma("unroll")                                                           \
        for (int ks = 0; ks < 2; ++ks) {                                            \
            short8 af[2], bf[4];                                                    \
            _Pragma("unroll")                                                       \
            for (int i = 0; i < 2; ++i) {                                           \
                int row = wm + i * 16 + (lane & 15);                                \
                int ch  = (ks * 4 + (lane >> 4)) ^ (row & 7);                       \
                af[i] = *(const short8*)&As[(buf) * 4096 + row * 64 + ch * 8];      \
            }                                                                       \
            _Pragma("unroll")                                                       \
            for (int j = 0; j < 4; ++j) {                                           \
                int row = wn + j * 16 + (lane & 15);                                \
                int ch  = (ks * 4 + (lane >> 4)) ^ (row & 7);                       \
                bf[j] = *(const short8*)&Bs[(buf) * 8192 + row * 64 + ch * 8];      \
            }                                                                       \
            _Pragma("unroll")                                                       \
            for (int i = 0; i < 2; ++i)                                             \
                _Pragma("unroll")                                                   \
                for (int j = 0; j < 4; ++j)                                         \
                    acc[i][j] = __builtin_amdgcn_mfma_f32_16x16x32_bf16(            \
                        af[i], bf[j], acc[i][j], 0, 0, 0);                          \
        }                                                                           \
    }

    if constexpr (DEPTH == 2) {
        STAGE(0, 0);
        __syncthreads();
        int cur = 0;
        for (int k0 = 0; k0 < K; k0 += 64) {
            if (k0 + 64 < K) STAGE(cur ^ 1, k0 + 64);
            COMPUTE(cur);
            __syncthreads();
            cur ^= 1;
        }
    } else {
        STAGE(0, 0);
        STAGE(1, 64);
        asm volatile("s_waitcnt vmcnt(6)" ::: "memory");
        __builtin_amdgcn_sched_barrier(0);
        __builtin_amdgcn_s_barrier();
        int cur = 0, stg = 2;
        for (int tt = 0; tt < nt; ++tt) {
            if (tt + 2 < nt) STAGE(stg, (tt + 2) << 6);
            COMPUTE(cur);
            if (tt + 1 < nt) {
                if (tt + 2 < nt) { asm volatile("s_waitcnt vmcnt(6)" ::: "memory"); }
                else             { asm volatile("s_waitcnt vmcnt(0)" ::: "memory"); }
                __builtin_amdgcn_sched_barrier(0);
                __builtin_amdgcn_s_barrier();
                __builtin_amdgcn_sched_barrier(0);
            }
            cur = (cur + 1 == DEPTH) ? 0 : cur + 1;
            stg = (stg + 1 == DEPTH) ? 0 : stg + 1;
        }
    }
#undef STAGE
#undef COMPUTE

    const int colb = n0 + wn + (lane & 15);
    const int rowb = m0 + wm + ((lane >> 4) * 4);
#pragma unroll
    for (int i = 0; i < 2; ++i) {
#pragma unroll
        for (int j = 0; j < 4; ++j) {
            const int col = colb + j * 16;
            const float bv = bias[col];
#pragma unroll
            for (int r = 0; r < 4; ++r) {
                const int row = rowb + i * 16 + r;
                float v = acc[i][j][r] + bv;
                if constexpr (ADD_POS) v += pos[(size_t)(row % LSEQ) * N + col];
                if constexpr (RES == 1) v += ((const float*)res)[(size_t)row * N + col];
                if constexpr (RES == 2) v += b2f(((const short*)res)[(size_t)row * N + col]);
                if constexpr (LEAKY)   v = v >= 0.f ? v : 0.01f * v;
                if constexpr (OUT_F32) ((float*)Cout)[(size_t)row * N + col] = v;
                else                   ((short*)Cout)[(size_t)row * N + col] = f2b(v);
            }
        }
    }
}

// ---------------- LayerNorm over E=768, input f32, outputs bf16 (+optional f32 copy) ----------------
__global__ __launch_bounds__(256)
void ln_kernel(const float* __restrict__ h, const float* __restrict__ g,
               const float* __restrict__ bbias, short* __restrict__ outb,
               float* __restrict__ outf)
{
    const int row = blockIdx.x;
    const float* x = h + (size_t)row * EMB;
    const int t = threadIdx.x;
    float v0 = x[t], v1 = x[t + 256], v2 = x[t + 512];
    float s  = v0 + v1 + v2;
    float ss = v0 * v0 + v1 * v1 + v2 * v2;
#pragma unroll
    for (int m = 1; m < 64; m <<= 1) {
        s  += __shfl_xor(s, m, 64);
        ss += __shfl_xor(ss, m, 64);
    }
    __shared__ float red[8];
    if ((t & 63) == 0) { red[t >> 6] = s; red[4 + (t >> 6)] = ss; }
    __syncthreads();
    float S  = red[0] + red[1] + red[2] + red[3];
    float SS = red[4] + red[5] + red[6] + red[7];
    float mean = S * (1.f / 768.f);
    float var  = SS * (1.f / 768.f) - mean * mean;
    float rstd = rsqrtf(var + 1e-5f);
    const size_t base = (size_t)row * EMB;
#pragma unroll
    for (int q = 0; q < 3; ++q) {
        int e = t + q * 256;
        float v = (q == 0 ? v0 : (q == 1 ? v1 : v2));
        float y = (v - mean) * rstd * g[e] + bbias[e];
        outb[base + e] = f2b(y);
        if (outf) outf[base + e] = y;
    }
}

// ---------------- per-layer K/V repack: kp[bh][l][d] (row-swizzled), vt[bh][d][l] (row-swizzled) ----
__global__ __launch_bounds__(256)
void repack_kv(const short* __restrict__ qkv, short* __restrict__ kp, short* __restrict__ vt)
{
    const int kt = blockIdx.x, bh = blockIdx.y;
    const int b = bh / 12, h = bh % 12;
    const int t = threadIdx.x;
#pragma unroll
    for (int i = 0; i < 2; ++i) {
        int flat = i * 256 + t;
        int key = flat >> 3, c = flat & 7;
        short8 vK = *(const short8*)(qkv + ((size_t)(b * LSEQ) + kt * 64 + key) * 2304 + 768 + h * 64 + c * 8);
        *(short8*)(kp + ((size_t)bh * LSEQ + kt * 64 + key) * 64 + 8 * (c ^ (key & 7))) = vK;
    }
    __shared__ short tile[64][65];
    const int tx = t & 63, ty = t >> 6;
#pragma unroll
    for (int r = 0; r < 16; ++r) {
        int k = ty * 16 + r;
        tile[k][tx] = qkv[((size_t)(b * LSEQ) + kt * 64 + k) * 2304 + 1536 + h * 64 + tx];
    }
    __syncthreads();
#pragma unroll
    for (int r = 0; r < 16; ++r) {
        int d = ty * 16 + r;
        vt[((size_t)bh * 64 + d) * LSEQ + kt * 64 + (tx ^ ((d & 7) << 3))] = tile[tx][d];
    }
}

// ---------------- MFMA flash attention. grid (9 qtiles, 96 bh), block 256 = 4 waves ----------------
__global__ __launch_bounds__(256)
void attn_mfma(const short* __restrict__ qkv, const short* __restrict__ kp,
               const short* __restrict__ vt, short* __restrict__ oout, int causal)
{
    const int qt = blockIdx.x, bh = blockIdx.y;
    const int b = bh / 12, h = bh % 12;
    const int t = threadIdx.x, lane = t & 63, w = t >> 6;

    __shared__ short Ks[64 * 64];
    __shared__ short Vs[64 * 64];
    __shared__ short Plds[4][16][72];

    const int nrow = lane & 15;
    const int kch  = (lane >> 4) * 8;
    const int swz  = (lane & 7) << 3;

    short8 aq[2];
    {
        const short* qrow = qkv + ((size_t)(b * LSEQ) + qt * 64 + w * 16 + nrow) * 2304 + h * 64 + kch;
        aq[0] = *(const short8*)qrow;
        aq[1] = *(const short8*)(qrow + 32);
    }

    float m[4], lsum[4];
    floatx4 oacc[4];
#pragma unroll
    for (int r = 0; r < 4; ++r) { m[r] = -3e38f; lsum[r] = 0.f; }
#pragma unroll
    for (int j = 0; j < 4; ++j) oacc[j] = (floatx4){0.f, 0.f, 0.f, 0.f};

    const int ktend = causal ? qt : 8;
    const short* ksrc = kp + ((size_t)bh * LSEQ) * 64;
    const short* vsrc = vt + ((size_t)bh * 64) * LSEQ;

    for (int kt = 0; kt <= ktend; ++kt) {
        __syncthreads();
        {
            const short* kt_src = ksrc + (size_t)(kt * 64) * 64;
            GLDS16(kt_src + (size_t)t * 8,          &Ks[(size_t)t * 8]);
            GLDS16(kt_src + (size_t)(t + 256) * 8,  &Ks[(size_t)(t + 256) * 8]);
            int f0 = t, f1 = t + 256;
            GLDS16(vsrc + (size_t)(f0 >> 3) * LSEQ + kt * 64 + (f0 & 7) * 8, &Vs[(size_t)f0 * 8]);
            GLDS16(vsrc + (size_t)(f1 >> 3) * LSEQ + kt * 64 + (f1 & 7) * 8, &Vs[(size_t)f1 * 8]);
        }
        __syncthreads();

        floatx4 sc[4];
#pragma unroll
        for (int j = 0; j < 4; ++j) sc[j] = (floatx4){0.f, 0.f, 0.f, 0.f};
#pragma unroll
        for (int s = 0; s < 2; ++s) {
#pragma unroll
            for (int j = 0; j < 4; ++j) {
                short8 bk = *(const short8*)&Ks[(16 * j + nrow) * 64 + ((kch + 32 * s) ^ swz)];
                sc[j] = __builtin_amdgcn_mfma_f32_16x16x32_bf16(aq[s], bk, sc[j], 0, 0, 0);
            }
        }
        float sv[4][4];
#pragma unroll
        for (int j = 0; j < 4; ++j)
#pragma unroll
            for (int r = 0; r < 4; ++r) {
                float v = sc[j][r] * 0.125f;
                if (causal && kt == qt) {
                    int key = kt * 64 + 16 * j + nrow;
                    int qr  = qt * 64 + w * 16 + (lane >> 4) * 4 + r;
                    if (key > qr) v = -1e12f;
                }
                sv[j][r] = v;
            }
#pragma unroll
        for (int r = 0; r < 4; ++r) {
            float tm = fmaxf(fmaxf(sv[0][r], sv[1][r]), fmaxf(sv[2][r], sv[3][r]));
            tm = fmaxf(tm, __shfl_xor(tm, 1, 64));
            tm = fmaxf(tm, __shfl_xor(tm, 2, 64));
            tm = fmaxf(tm, __shfl_xor(tm, 4, 64));
            tm = fmaxf(tm, __shfl_xor(tm, 8, 64));
            float nm = fmaxf(m[r], tm);
            float c  = __expf(m[r] - nm);
            m[r] = nm;
            float ps = 0.f;
#pragma unroll
            for (int j = 0; j < 4; ++j) {
                float p = __expf(sv[j][r] - nm);
                sv[j][r] = p;
                ps += p;
            }
            lsum[r] = lsum[r] * c + ps;
#pragma unroll
            for (int j = 0; j < 4; ++j) oacc[j][r] *= c;
        }
#pragma unroll
        for (int j = 0; j < 4; ++j)
#pragma unroll
            for (int r = 0; r < 4; ++r)
                Plds[w][(lane >> 4) * 4 + r][16 * j + nrow] = f2b(sv[j][r]);
        short8 ap[2];
#pragma unroll
        for (int s = 0; s < 2; ++s)
            ap[s] = *(const short8*)&Plds[w][nrow][kch + 32 * s];
#pragma unroll
        for (int s = 0; s < 2; ++s) {
#pragma unroll
            for (int j = 0; j < 4; ++j) {
                short8 bv = *(const short8*)&Vs[(16 * j + nrow) * 64 + ((kch + 32 * s) ^ swz)];
                oacc[j] = __builtin_amdgcn_mfma_f32_16x16x32_bf16(ap[s], bv, oacc[j], 0, 0, 0);
            }
        }
    }

    float inv[4];
#pragma unroll
    for (int r = 0; r < 4; ++r) {
        float L = lsum[r];
        L += __shfl_xor(L, 1, 64);
        L += __shfl_xor(L, 2, 64);
        L += __shfl_xor(L, 4, 64);
        L += __shfl_xor(L, 8, 64);
        inv[r] = 1.f / L;
    }
#pragma unroll
    for (int j = 0; j < 4; ++j)
#pragma unroll
        for (int r = 0; r < 4; ++r) {
            size_t lq = (size_t)qt * 64 + w * 16 + (lane >> 4) * 4 + r;
            oout[((size_t)bh * LSEQ + lq) * 64 + 16 * j + nrow] = f2b(oacc[j][r] * inv[r]);
        }
}

// ---------------- transposes ----------------
__global__ void transpose_f2b(const float* __restrict__ in, short* __restrict__ out,
                              int R, int C, long long ibs, long long obs)
{
    __shared__ float tile[32][33];
    const int b = blockIdx.z;
    const float* inb = in + (long long)b * ibs;
    short* outb = out + (long long)b * obs;
    const int r0 = blockIdx.y * 32, c0 = blockIdx.x * 32;
    const int tx = threadIdx.x, ty = threadIdx.y;
#pragma unroll
    for (int i = 0; i < 32; i += 8) tile[ty + i][tx] = inb[(size_t)(r0 + ty + i) * C + c0 + tx];
    __syncthreads();
#pragma unroll
    for (int i = 0; i < 32; i += 8) outb[(size_t)(c0 + ty + i) * R + r0 + tx] = f2b(tile[tx][ty + i]);
}

__global__ void transpose_f2f(const float* __restrict__ in, float* __restrict__ out,
                              int R, int C, long long ibs, long long obs)
{
    __shared__ float tile[32][33];
    const int b = blockIdx.z;
    const float* inb = in + (long long)b * ibs;
    float* outb = out + (long long)b * obs;
    const int r0 = blockIdx.y * 32, c0 = blockIdx.x * 32;
    const int tx = threadIdx.x, ty = threadIdx.y;
#pragma unroll
    for (int i = 0; i < 32; i += 8) tile[ty + i][tx] = inb[(size_t)(r0 + ty + i) * C + c0 + tx];
    __syncthreads();
#pragma unroll
    for (int i = 0; i < 32; i += 8) outb[(size_t)(c0 + ty + i) * R + r0 + tx] = tile[tx][ty + i];
}

// ---------------- misc small kernels ----------------
__global__ void concat_qkv_bias(const float* __restrict__ bq, const float* __restrict__ bk,
                                const float* __restrict__ bv, float* __restrict__ out)
{
    int i = blockIdx.x * 256 + threadIdx.x;
    int layer = i / 2304, j = i % 2304;
    float v;
    if (j < 768)       v = bq[layer * 768 + j];
    else if (j < 1536) v = bk[layer * 768 + j - 768];
    else               v = bv[layer * 768 + j - 1536];
    out[i] = v;
}

__global__ void im2col_kernel(const float* __restrict__ x, short* __restrict__ xcol)
{
    const size_t idx = (size_t)blockIdx.x * 256 + threadIdx.x;
    const int k = (int)(idx % 768);
    const size_t m = idx / 768;
    const int c  = k >> 8;
    const int ky = (k >> 4) & 15;
    const int kx = k & 15;
    const int b  = (int)(m / 576);
    const int l  = (int)(m % 576);
    const int ph = l / 24, pw = l % 24;
    xcol[idx] = f2b(x[((size_t)(b * 3 + c) * 384 + ph * 16 + ky) * 384 + pw * 16 + kx]);
}

__global__ void cast_f32_b16(const float* __restrict__ in, short* __restrict__ out, int n)
{
    int i = blockIdx.x * 256 + threadIdx.x;
    if (i < n) out[i] = f2b(in[i]);
}

// ---------------- host launcher ----------------
extern "C" void kernel_launch(void* const* d_in, const int* in_sizes, int n_in,
                              void* d_out, int out_size, void* d_ws, size_t ws_size,
                              hipStream_t stream)
{
    const float* x      = (const float*)d_in[0];
    const float* conv_w = (const float*)d_in[1];
    const float* conv_b = (const float*)d_in[2];
    const float* pos    = (const float*)d_in[3];
    const float* ln0_s  = (const float*)d_in[4];
    const float* ln0_b  = (const float*)d_in[5];
    const float* Wq     = (const float*)d_in[6];
    const float* bq     = (const float*)d_in[7];
    const float* Wk     = (const float*)d_in[8];
    const float* bk     = (const float*)d_in[9];
    const float* Wv     = (const float*)d_in[10];
    const float* bv     = (const float*)d_in[11];
    const float* Wo     = (const float*)d_in[12];
    const float* bo     = (const float*)d_in[13];
    const float* ln1_s  = (const float*)d_in[14];
    const float* ln1_b  = (const float*)d_in[15];
    const float* W1     = (const float*)d_in[16];
    const float* b1     = (const float*)d_in[17];
    const float* W2     = (const float*)d_in[18];
    const float* b2     = (const float*)d_in[19];
    const float* proj_w = (const float*)d_in[20];
    const float* proj_b = (const float*)d_in[21];

    char* ws = (char*)d_ws;
    short* qkvT  = (short*)(ws);                    // [8][2304][768] bf16
    short* woT   = (short*)(ws + 28311552);         // [8][768][768]
    short* w1T   = (short*)(ws + 37748736);         // [8][3072][768]
    short* w2T   = (short*)(ws + 75497472);         // [8][768][3072]
    short* projT = (short*)(ws + 113246208);        // [768][768]
    float* qkvb  = (float*)(ws + 114425856);        // [8][2304] f32
    short* tmpA  = (short*)(ws + 114499584);        // xcol / m1 bf16 [4608][3072]; kp/vt overlay; yf f32
    float* h     = (float*)(ws + 142811136);        // residual stream f32 [4608][768]
    short* xn    = (short*)(ws + 156966912);        // LN0 out bf16; hb at end
    short* xrb   = (short*)(ws + 164044800);        // LN1 out bf16
    short* qkv   = (short*)(ws + 185278464);        // [4608][2304] bf16
    short* o     = (short*)(ws + 206512128);        // attn out (scrambled) bf16
    short* convB = (short*)(ws + 213590016);        // conv_w cast bf16 [768][768]

    short* kp = tmpA;                               // [96][576][64] bf16
    short* vt = tmpA + 3538944;                     // [96][64][576] bf16

    dim3 tb(32, 8);
    transpose_f2b<<<dim3(24, 24, 8), tb, 0, stream>>>(Wq, qkvT,           768, 768, 589824, 1769472);
    transpose_f2b<<<dim3(24, 24, 8), tb, 0, stream>>>(Wk, qkvT + 589824,  768, 768, 589824, 1769472);
    transpose_f2b<<<dim3(24, 24, 8), tb, 0, stream>>>(Wv, qkvT + 1179648, 768, 768, 589824, 1769472);
    transpose_f2b<<<dim3(24, 24, 8), tb, 0, stream>>>(Wo, woT,            768, 768, 589824, 589824);
    transpose_f2b<<<dim3(96, 24, 8), tb, 0, stream>>>(W1, w1T,            768, 3072, 2359296, 2359296);
    transpose_f2b<<<dim3(24, 96, 8), tb, 0, stream>>>(W2, w2T,            3072, 768, 2359296, 2359296);
    transpose_f2b<<<dim3(24, 24, 1), tb, 0, stream>>>(proj_w, projT,      768, 768, 0, 0);
    cast_f32_b16<<<2304, 256, 0, stream>>>(conv_w, convB, 589824);
    concat_qkv_bias<<<72, 256, 0, stream>>>(bq, bk, bv, qkvb);

    // patch embed: im2col + GEMM(convB as Bt) + conv_b + pos  -> h (f32)
    im2col_kernel<<<13824, 256, 0, stream>>>(x, tmpA);
    gemm_bt<3, 0, true, false, true><<<dim3(6, 72), 256, 0, stream>>>(
        tmpA, convB, conv_b, pos, nullptr, h, 768, 768);

    for (int i = 0; i < NLAYERS; ++i) {
        ln_kernel<<<4608, 256, 0, stream>>>(h, ln0_s + i * 768, ln0_b + i * 768, xn, nullptr);
        gemm_bt<2, 0, false, false, false><<<dim3(18, 72), 256, 0, stream>>>(
            xn, qkvT + (size_t)i * 1769472, qkvb + i * 2304, nullptr, nullptr, qkv, 2304, 768);
        repack_kv<<<dim3(9, 96), 256, 0, stream>>>(qkv, kp, vt);
        attn_mfma<<<dim3(9, 96), 256, 0, stream>>>(qkv, kp, vt, o, i == 0 ? 1 : 0);
        gemm_bt<3, 1, false, false, true><<<dim3(6, 72), 256, 0, stream>>>(
            o, woT + (size_t)i * 589824, bo + i * 768, nullptr, h, h, 768, 768);
        ln_kernel<<<4608, 256, 0, stream>>>(h, ln1_s + i * 768, ln1_b + i * 768, xrb, nullptr);
        gemm_bt<2, 0, false, true, false><<<dim3(24, 72), 256, 0, stream>>>(
            xrb, w1T + (size_t)i * 2359296, b1 + i * 3072, nullptr, nullptr, tmpA, 3072, 768);
        gemm_bt<3, 2, false, false, true><<<dim3(6, 72), 256, 0, stream>>>(
            tmpA, w2T + (size_t)i * 2359296, b2 + i * 768, nullptr, xrb, h, 768, 3072);
    }

    // final projection + output scramble (B, L, CPP) -> (B, CPP, L) flat
    short* hb = xn;
    float* yf = (float*)tmpA;
    cast_f32_b16<<<13824, 256, 0, stream>>>(h, hb, 4608 * 768);
    gemm_bt<3, 0, false, false, true><<<dim3(6, 72), 256, 0, stream>>>(
        hb, projT, proj_b, nullptr, nullptr, yf, 768, 768);
    transpose_f2f<<<dim3(24, 18, 8), tb, 0, stream>>>(yf, (float*)d_out, 576, 768, 442368, 442368);
}